// Round 6
// baseline (1742.614 us; speedup 1.0000x reference)
//
#include <hip/hip_runtime.h>
#include <hip/hip_bf16.h>

#define N_NODES  60000
#define N_EDGES  240000
#define N_REL    4
#define N_GRAPHS 128
#define D_IN     768
#define D_H      256
#define N_LAYERS 6
#define M_PAD    60032            // 469 * 128
#define N_TOT    1280             // L0: 256 root + 4*256 msg; also W k-stride
#define BM_L     64               // fused layer: dst rows per block
#define LDM      264              // mean tile row stride (+16B pad)

static inline int cdiv(int a, int b) { return (a + b - 1) / b; }

typedef __attribute__((ext_vector_type(8))) short short8;
typedef __attribute__((ext_vector_type(4))) float f32x4;

__device__ __forceinline__ float bf2f(unsigned short u) {
    union { unsigned int i; float f; } c; c.i = ((unsigned int)u) << 16; return c.f;
}
__device__ __forceinline__ unsigned short f2bf(float f) {
    union { float f; unsigned int i; } c; c.f = f;
    unsigned int i = c.i;
    unsigned int r = (i + 0x7FFFu + ((i >> 16) & 1u)) >> 16;   // RNE
    return (unsigned short)r;
}

__device__ __forceinline__ void gload16(const void* g, void* l) {
    __builtin_amdgcn_global_load_lds((const __attribute__((address_space(1))) void*)g,
                                     (__attribute__((address_space(3))) void*)l, 16, 0, 0);
}

// ---------------------------------------------------------------------------
// Layer-0 GEMM (transform-first): A[M_PAD,768] bf16 @ Wt0[1280,768]^T.
// Flat grid, XCD-swizzled: a row-block's 5 col-blocks share b%8 -> same XCD.
// ---------------------------------------------------------------------------
__global__ __launch_bounds__(512) void gemm_l0(
    const unsigned short* __restrict__ A,
    const unsigned short* __restrict__ Bt,
    const float* __restrict__ bias,
    unsigned short* __restrict__ out_root,
    unsigned short* __restrict__ out_msg,
    int K)
{
    __shared__ unsigned short As[128 * 32];
    __shared__ unsigned short Bs[256 * 32];

    const int tid  = threadIdx.x;
    const int wave = tid >> 6, lane = tid & 63;

    int b = blockIdx.x;
    int bm, bn;
    if (b < 2320) { int grp = b / 40, rem = b % 40; bm = (grp * 8 + (rem & 7)) * 128; bn = (rem >> 3) * 256; }
    else          { int rem = b - 2320; bm = (464 + rem % 5) * 128; bn = (rem / 5) * 256; }

    const int wm = (wave & 1) * 64, wn = (wave >> 1) * 64;

    const int lr = lane >> 2;
    const int kg = ((lane & 3) ^ ((lr ^ (lr >> 2)) & 3)) * 8;   // swizzled k-chunk
    const unsigned short* gsrc[3];
    unsigned short* ldst[3];
    #pragma unroll
    for (int j = 0; j < 3; ++j) {
        int g = wave * 3 + j;
        if (g < 8) {
            gsrc[j] = A + (size_t)(bm + g * 16 + lr) * K + kg;
            ldst[j] = As + g * 16 * 32;
        } else {
            gsrc[j] = Bt + (size_t)(bn + (g - 8) * 16 + lr) * K + kg;
            ldst[j] = Bs + (g - 8) * 16 * 32;
        }
    }

    f32x4 acc[4][4] = {};
    const int fr = lane & 15;
    const int qsw = (((lane >> 4) ^ fr ^ (fr >> 2)) & 3) * 8;

    for (int k0 = 0; k0 < K; k0 += 32) {
        gload16(gsrc[0] + k0, ldst[0]);
        gload16(gsrc[1] + k0, ldst[1]);
        gload16(gsrc[2] + k0, ldst[2]);
        __syncthreads();

        short8 a[4], bb[4];
        #pragma unroll
        for (int t = 0; t < 4; ++t) {
            a[t]  = *(const short8*)&As[(wm + t * 16 + fr) * 32 + qsw];
            bb[t] = *(const short8*)&Bs[(wn + t * 16 + fr) * 32 + qsw];
        }
        #pragma unroll
        for (int mt = 0; mt < 4; ++mt)
            #pragma unroll
            for (int nt = 0; nt < 4; ++nt)
                acc[mt][nt] = __builtin_amdgcn_mfma_f32_16x16x32_bf16(
                    a[mt], bb[nt], acc[mt][nt], 0, 0, 0);
        __syncthreads();
    }

    const bool is_root = (bn == 0);   // block-uniform
    #pragma unroll
    for (int mt = 0; mt < 4; ++mt) {
        #pragma unroll
        for (int nt = 0; nt < 4; ++nt) {
            int col = bn + wn + nt * 16 + fr;
            float bv = bias[col];
            #pragma unroll
            for (int r = 0; r < 4; ++r) {
                int row = bm + wm + mt * 16 + ((lane >> 4) << 2) + r;
                float v = acc[mt][nt][r] + bv;
                if (is_root) out_root[(size_t)row * 256 + col] = f2bf(v);
                else         out_msg[(size_t)row * 1024 + (col - 256)] = f2bf(v);
            }
        }
    }
}

// ---------------------------------------------------------------------------
// Fused RGCN mid-layer, v3. Phases r in {0..3 rel-mean, 4 root}:
//  - W phase-slice preloaded to VGPRs (wave-private, issued BEFORE the barrier
//    so L2 latency hides behind barrier+gather).
//  - Gather is WAVE-PER-NODE: node/lo/hi/scale wave-uniform (no divergence),
//    each edge = one coalesced 512B load (64 lanes x ushort4).
//  - Mean tile -> LDS, 2 barriers/phase, then 8 MFMA K-steps.
// ---------------------------------------------------------------------------
__global__ __launch_bounds__(512) void rgcn_layer(
    const unsigned short* __restrict__ h,     // [M_PAD, 256]
    const unsigned short* __restrict__ Wl,    // [256 out][1280 k]
    const float* __restrict__ bias,           // [256]
    const int* __restrict__ rp4,              // [4*N_NODES + 1]
    const int* __restrict__ e_srcs,           // [E] srcs sorted by (dst, rel)
    const float* __restrict__ inv4,           // [N_NODES*4]
    unsigned short* __restrict__ h_out)       // [M_PAD, 256]
{
    __shared__ unsigned short mt[BM_L * LDM];   // 33,792 B

    const int tid  = threadIdx.x;
    const int wave = tid >> 6, lane = tid & 63;
    const int bm = blockIdx.x * BM_L;

    const int fr   = lane & 15;                  // MFMA m / n index
    const int q8   = (lane >> 4) * 8;            // MFMA k offset (shorts)
    const int wcol = wave * 32;                  // wave's 32 output cols

    f32x4 acc[4][2] = {};

    for (int r = 0; r < 5; ++r) {
        // ---- preload W phase fragments (independent of LDS/barrier) ----
        const int rOff = r << 8;
        short8 bf0[8], bf1[8];
        {
            const unsigned short* w0p = Wl + (size_t)(wcol + fr) * N_TOT + rOff + q8;
            const unsigned short* w1p = Wl + (size_t)(wcol + 16 + fr) * N_TOT + rOff + q8;
            #pragma unroll
            for (int kk = 0; kk < 8; ++kk) {
                bf0[kk] = *(const short8*)(w0p + kk * 32);
                bf1[kk] = *(const short8*)(w1p + kk * 32);
            }
        }

        __syncthreads();   // previous phase's mt reads complete

        // ---- gather: wave handles 8 nodes serially, coalesced edge reads ----
        #pragma unroll 1
        for (int j = 0; j < 8; ++j) {
            int ln = wave * 8 + j;
            int node = bm + ln;
            float4 a = make_float4(0.f, 0.f, 0.f, 0.f);
            if (node < N_NODES) {
                if (r < 4) {
                    int lo = rp4[node * 4 + r];        // wave-uniform
                    int hi = rp4[node * 4 + r + 1];
                    float sc = inv4[node * 4 + r];
                    int e = lo;
                    for (; e + 1 < hi; e += 2) {
                        ushort4 m0 = *(const ushort4*)&h[(size_t)e_srcs[e] * 256 + lane * 4];
                        ushort4 m1 = *(const ushort4*)&h[(size_t)e_srcs[e + 1] * 256 + lane * 4];
                        a.x += bf2f(m0.x) + bf2f(m1.x);
                        a.y += bf2f(m0.y) + bf2f(m1.y);
                        a.z += bf2f(m0.z) + bf2f(m1.z);
                        a.w += bf2f(m0.w) + bf2f(m1.w);
                    }
                    if (e < hi) {
                        ushort4 m0 = *(const ushort4*)&h[(size_t)e_srcs[e] * 256 + lane * 4];
                        a.x += bf2f(m0.x); a.y += bf2f(m0.y);
                        a.z += bf2f(m0.z); a.w += bf2f(m0.w);
                    }
                    a.x *= sc; a.y *= sc; a.z *= sc; a.w *= sc;
                } else {
                    ushort4 m0 = *(const ushort4*)&h[(size_t)node * 256 + lane * 4];
                    a.x = bf2f(m0.x); a.y = bf2f(m0.y);
                    a.z = bf2f(m0.z); a.w = bf2f(m0.w);
                }
            }
            ushort4 o;
            o.x = f2bf(a.x); o.y = f2bf(a.y); o.z = f2bf(a.z); o.w = f2bf(a.w);
            *(ushort4*)&mt[ln * LDM + lane * 4] = o;
        }
        __syncthreads();   // mt visible to all waves

        // ---- 8 MFMA K-steps (W already in VGPRs) ----
        #pragma unroll
        for (int kk = 0; kk < 8; ++kk) {
            short8 a4[4];
            #pragma unroll
            for (int i = 0; i < 4; ++i)
                a4[i] = *(const short8*)&mt[(i * 16 + fr) * LDM + kk * 32 + q8];
            #pragma unroll
            for (int i = 0; i < 4; ++i) {
                acc[i][0] = __builtin_amdgcn_mfma_f32_16x16x32_bf16(a4[i], bf0[kk], acc[i][0], 0, 0, 0);
                acc[i][1] = __builtin_amdgcn_mfma_f32_16x16x32_bf16(a4[i], bf1[kk], acc[i][1], 0, 0, 0);
            }
        }
    }

    // epilogue: +bias, ReLU, bf16
    #pragma unroll
    for (int i = 0; i < 4; ++i) {
        #pragma unroll
        for (int nt = 0; nt < 2; ++nt) {
            int col = wcol + nt * 16 + fr;
            float bv = bias[col];
            #pragma unroll
            for (int rg = 0; rg < 4; ++rg) {
                int row = bm + i * 16 + ((lane >> 4) << 2) + rg;
                float v = fmaxf(acc[i][nt][rg] + bv, 0.f);
                h_out[(size_t)row * 256 + col] = f2bf(v);
            }
        }
    }
}

// ---------------------------------------------------------------------------
// Prep kernels
// ---------------------------------------------------------------------------
__global__ void convert_x(const float* __restrict__ x, unsigned short* __restrict__ xb) {
    size_t i = ((size_t)blockIdx.x * 256 + threadIdx.x) * 4;
    if (i >= (size_t)M_PAD * D_IN) return;
    ushort4 o;
    if (i < (size_t)N_NODES * D_IN) {
        float4 v = *(const float4*)&x[i];
        o.x = f2bf(v.x); o.y = f2bf(v.y); o.z = f2bf(v.z); o.w = f2bf(v.w);
    } else {
        o.x = o.y = o.z = o.w = 0;
    }
    *(ushort4*)&xb[i] = o;
}

__global__ void pack_w0(const float* __restrict__ root0, const float* __restrict__ w0,
                        unsigned short* __restrict__ Wt0) {
    int idx = blockIdx.x * 256 + threadIdx.x;            // Wt0[n][k], [1280 x 768]
    if (idx >= N_TOT * D_IN) return;
    int k = idx % D_IN, n = idx / D_IN;
    float v = (n < 256) ? root0[k * 256 + n]
                        : w0[(((n >> 8) - 1) * D_IN + k) * 256 + (n & 255)];
    Wt0[idx] = f2bf(v);
}

// WtR[l][n][k]: k<1024 -> w_rest[l][k>>8][k&255][n]; k>=1024 -> root_rest[l][k-1024][n]
__global__ void pack_wr(const float* __restrict__ root_rest, const float* __restrict__ w_rest,
                        unsigned short* __restrict__ WtR) {
    int idx = blockIdx.x * 256 + threadIdx.x;
    if (idx >= 5 * 256 * N_TOT) return;
    int k = idx % N_TOT; int t = idx / N_TOT; int n = t & 255; int l = t >> 8;
    float v = (k < 1024)
        ? w_rest[(((l * 4 + (k >> 8)) * 256) + (k & 255)) * 256 + n]
        : root_rest[(l * 256 + (k - 1024)) * 256 + n];
    WtR[idx] = f2bf(v);
}

__global__ void build_bias(const float* __restrict__ b0, float* __restrict__ eb) {
    int i = blockIdx.x * 256 + threadIdx.x;
    if (i < N_TOT) eb[i] = (i < 256) ? b0[i] : 0.f;
}

// ---------------------------------------------------------------------------
// (dst, rel)-sorted CSR over 4*N segments
// ---------------------------------------------------------------------------
__global__ void deg4_count(const int* __restrict__ dst, const int* __restrict__ rel,
                           int* __restrict__ deg4, int E) {
    int e = blockIdx.x * 256 + threadIdx.x;
    if (e < E) atomicAdd(&deg4[dst[e] * 4 + rel[e]], 1);
}

__global__ void invert4(const int* __restrict__ deg4, float* __restrict__ inv4, int n) {
    int i = blockIdx.x * 256 + threadIdx.x;
    if (i < n) inv4[i] = 1.0f / (float)max(deg4[i], 1);
}

__global__ __launch_bounds__(256) void block_sum(const int* __restrict__ deg,
                                                 int* __restrict__ bsum, int n) {
    __shared__ int s[256];
    int i = blockIdx.x * 256 + threadIdx.x;
    s[threadIdx.x] = (i < n) ? deg[i] : 0;
    __syncthreads();
    for (int o = 128; o > 0; o >>= 1) {
        if (threadIdx.x < o) s[threadIdx.x] += s[threadIdx.x + o];
        __syncthreads();
    }
    if (threadIdx.x == 0) bsum[blockIdx.x] = s[0];
}

__global__ __launch_bounds__(1024) void scan_bsum(const int* __restrict__ bsum,
                                                  int* __restrict__ boff, int nb) {
    __shared__ int s[1024];
    int t = threadIdx.x;
    int v0 = (t < nb) ? bsum[t] : 0;
    s[t] = v0;
    __syncthreads();
    for (int o = 1; o < 1024; o <<= 1) {
        int v = (t >= o) ? s[t - o] : 0;
        __syncthreads();
        s[t] += v;
        __syncthreads();
    }
    if (t < nb) boff[t] = s[t] - v0;   // exclusive
}

__global__ __launch_bounds__(256) void block_scan_write(
    const int* __restrict__ deg, const int* __restrict__ boff,
    int* __restrict__ row_ptr, int* __restrict__ cursor, int n, int total) {
    __shared__ int s[256];
    int t = threadIdx.x;
    int i = blockIdx.x * 256 + t;
    int v = (i < n) ? deg[i] : 0;
    s[t] = v;
    __syncthreads();
    for (int o = 1; o < 256; o <<= 1) {
        int u = (t >= o) ? s[t - o] : 0;
        __syncthreads();
        s[t] += u;
        __syncthreads();
    }
    int excl = s[t] - v + boff[blockIdx.x];
    if (i < n) { row_ptr[i] = excl; cursor[i] = excl; }
    if (blockIdx.x == 0 && t == 0) row_ptr[n] = total;
}

__global__ void place_edges4(const int* __restrict__ dst, const int* __restrict__ src,
                             const int* __restrict__ rel, int* __restrict__ cursor,
                             int* __restrict__ e_srcs, int E) {
    int e = blockIdx.x * 256 + threadIdx.x;
    if (e < E) {
        int p = atomicAdd(&cursor[dst[e] * 4 + rel[e]], 1);
        e_srcs[p] = src[e];
    }
}

// ---------------------------------------------------------------------------
// Layer-0 aggregate: h0 = relu(root[n] + sum_r inv_r * sum_e msg[src, r])
// ---------------------------------------------------------------------------
__global__ __launch_bounds__(256) void aggregate0(
    const unsigned short* __restrict__ rootb,   // [M_PAD,256]
    const unsigned short* __restrict__ msg,     // [M_PAD,1024]
    const int* __restrict__ rp4, const int* __restrict__ e_srcs,
    const float* __restrict__ inv4,
    unsigned short* __restrict__ h_out)         // [M_PAD,256]
{
    int node = blockIdx.x * 4 + (threadIdx.x >> 6);
    if (node >= N_NODES) return;
    int lane = threadIdx.x & 63;
    float4 iv = *(const float4*)&inv4[(size_t)node * 4];

    ushort4 rt = *(const ushort4*)&rootb[(size_t)node * 256 + lane * 4];
    float4 acc = make_float4(bf2f(rt.x), bf2f(rt.y), bf2f(rt.z), bf2f(rt.w));

    #pragma unroll
    for (int r = 0; r < 4; ++r) {
        int lo = rp4[(size_t)node * 4 + r], hi = rp4[(size_t)node * 4 + r + 1];
        float f = (r == 0) ? iv.x : (r == 1) ? iv.y : (r == 2) ? iv.z : iv.w;
        float4 s4 = make_float4(0, 0, 0, 0);
        int e = lo;
        for (; e + 1 < hi; e += 2) {
            ushort4 m0 = *(const ushort4*)&msg[(size_t)e_srcs[e] * 1024 + (r << 8) + lane * 4];
            ushort4 m1 = *(const ushort4*)&msg[(size_t)e_srcs[e + 1] * 1024 + (r << 8) + lane * 4];
            s4.x += bf2f(m0.x) + bf2f(m1.x);
            s4.y += bf2f(m0.y) + bf2f(m1.y);
            s4.z += bf2f(m0.z) + bf2f(m1.z);
            s4.w += bf2f(m0.w) + bf2f(m1.w);
        }
        if (e < hi) {
            ushort4 m0 = *(const ushort4*)&msg[(size_t)e_srcs[e] * 1024 + (r << 8) + lane * 4];
            s4.x += bf2f(m0.x); s4.y += bf2f(m0.y);
            s4.z += bf2f(m0.z); s4.w += bf2f(m0.w);
        }
        acc.x += s4.x * f; acc.y += s4.y * f;
        acc.z += s4.z * f; acc.w += s4.w * f;
    }
    ushort4 o;
    o.x = f2bf(fmaxf(acc.x, 0.f));
    o.y = f2bf(fmaxf(acc.y, 0.f));
    o.z = f2bf(fmaxf(acc.z, 0.f));
    o.w = f2bf(fmaxf(acc.w, 0.f));
    *(ushort4*)&h_out[(size_t)node * 256 + lane * 4] = o;
}

// ---------------------------------------------------------------------------
// Pooling + MLP head
// ---------------------------------------------------------------------------
__global__ __launch_bounds__(256) void pool_kernel(
    const unsigned short* __restrict__ h, const int* __restrict__ batch,
    float* __restrict__ g_feat)
{
    int g = blockIdx.x;
    int t = threadIdx.x;
    __shared__ int s_lo, s_hi;
    if (t == 0) {
        int lo = 0, hi = N_NODES;
        while (lo < hi) { int m = (lo + hi) >> 1; if (batch[m] < g) lo = m + 1; else hi = m; }
        s_lo = lo;
        int lo2 = lo, hi2 = N_NODES;
        while (lo2 < hi2) { int m = (lo2 + hi2) >> 1; if (batch[m] < g + 1) lo2 = m + 1; else hi2 = m; }
        s_hi = lo2;
    }
    __syncthreads();
    int lo = s_lo, hi = s_hi;
    float sum = 0.f, mx = 0.f;   // post-ReLU
    for (int n = lo; n < hi; ++n) {
        float v = bf2f(h[(size_t)n * 256 + t]);
        sum += v;
        mx = fmaxf(mx, v);
    }
    float cnt = (float)(hi - lo);
    g_feat[g * 512 + t]       = sum / fmaxf(cnt, 1.0f);
    g_feat[g * 512 + 256 + t] = (cnt > 0.f) ? mx : 0.f;
}

__global__ __launch_bounds__(128) void mlp_head(
    const float* __restrict__ g_feat,
    const float* __restrict__ fc1_w, const float* __restrict__ fc1_b,
    const float* __restrict__ fc2_w, const float* __restrict__ fc2_b,
    float* __restrict__ out)
{
    __shared__ float gf[512];
    __shared__ float partial[2];
    int g = blockIdx.x, t = threadIdx.x;
    for (int i = t; i < 512; i += 128) gf[i] = g_feat[g * 512 + i];
    __syncthreads();
    float acc = fc1_b[t];
    for (int i = 0; i < 512; ++i) acc += gf[i] * fc1_w[i * 128 + t];
    float h1 = fmaxf(acc, 0.f);
    float v = h1 * fc2_w[t];
    #pragma unroll
    for (int off = 32; off > 0; off >>= 1) v += __shfl_down(v, off);
    if ((t & 63) == 0) partial[t >> 6] = v;
    __syncthreads();
    if (t == 0) {
        float s = partial[0] + partial[1] + fc2_b[0];
        out[g] = 1.0f / (1.0f + expf(-s));
    }
}

// ---------------------------------------------------------------------------
// Launch
// ---------------------------------------------------------------------------
extern "C" void kernel_launch(void* const* d_in, const int* in_sizes, int n_in,
                              void* d_out, int out_size, void* d_ws, size_t ws_size,
                              hipStream_t stream) {
    const float* x          = (const float*)d_in[0];
    const int*   edge_index = (const int*)d_in[1];
    const int*   edge_attr  = (const int*)d_in[2];
    const int*   batch      = (const int*)d_in[3];
    const float* w0         = (const float*)d_in[4];
    const float* root0      = (const float*)d_in[5];
    const float* b0         = (const float*)d_in[6];
    const float* w_rest     = (const float*)d_in[7];
    const float* root_rest  = (const float*)d_in[8];
    const float* b_rest     = (const float*)d_in[9];
    const float* fc1_w      = (const float*)d_in[10];
    const float* fc1_b      = (const float*)d_in[11];
    const float* fc2_w      = (const float*)d_in[12];
    const float* fc2_b      = (const float*)d_in[13];
    float* out = (float*)d_out;

    const int* e_src = edge_index;
    const int* e_dst = edge_index + N_EDGES;

    char* p = (char*)d_ws;
    auto alloc = [&](size_t bytes) { char* q = p; p += (bytes + 255) & ~(size_t)255; return q; };
    unsigned short* x_bf   = (unsigned short*)alloc((size_t)M_PAD * D_IN * 2);   // 92 MB
    unsigned short* msgbuf = (unsigned short*)alloc((size_t)M_PAD * 1024 * 2);   // 123 MB
    unsigned short* hA     = (unsigned short*)alloc((size_t)M_PAD * 256 * 2);    // 31 MB
    unsigned short* hB     = (unsigned short*)alloc((size_t)M_PAD * 256 * 2);    // 31 MB
    unsigned short* Wt0    = (unsigned short*)alloc((size_t)N_TOT * D_IN * 2);
    unsigned short* WtR    = (unsigned short*)alloc((size_t)5 * 256 * N_TOT * 2);
    float*          ebias  = (float*)alloc(N_TOT * 4);
    float*          inv4   = (float*)alloc((size_t)N_NODES * 4 * 4);
    float*          g_feat = (float*)alloc((size_t)N_GRAPHS * 512 * 4);
    int*            deg4   = (int*)alloc((size_t)N_NODES * 4 * 4);
    int*            rp4    = (int*)alloc(((size_t)N_NODES * 4 + 1) * 4);
    int*            cursor4= (int*)alloc((size_t)N_NODES * 4 * 4);
    int*            bsum   = (int*)alloc(1024 * 4);
    int*            boff   = (int*)alloc(1024 * 4);
    int*            e_srcs = (int*)alloc((size_t)N_EDGES * 4);

    const int n4 = N_NODES * 4;                 // 240000
    const int nscan4 = cdiv(n4, 256);           // 938

    // --- prep ---
    hipMemsetAsync(deg4, 0, (size_t)n4 * 4, stream);
    convert_x<<<cdiv(M_PAD * D_IN / 4, 256), 256, 0, stream>>>(x, x_bf);
    pack_w0<<<cdiv(N_TOT * D_IN, 256), 256, 0, stream>>>(root0, w0, Wt0);
    pack_wr<<<cdiv(5 * 256 * N_TOT, 256), 256, 0, stream>>>(root_rest, w_rest, WtR);
    build_bias<<<cdiv(N_TOT, 256), 256, 0, stream>>>(b0, ebias);
    deg4_count<<<cdiv(N_EDGES, 256), 256, 0, stream>>>(e_dst, edge_attr, deg4, N_EDGES);
    invert4<<<cdiv(n4, 256), 256, 0, stream>>>(deg4, inv4, n4);
    block_sum<<<nscan4, 256, 0, stream>>>(deg4, bsum, n4);
    scan_bsum<<<1, 1024, 0, stream>>>(bsum, boff, nscan4);
    block_scan_write<<<nscan4, 256, 0, stream>>>(deg4, boff, rp4, cursor4, n4, N_EDGES);
    place_edges4<<<cdiv(N_EDGES, 256), 256, 0, stream>>>(e_dst, e_src, edge_attr,
                                                         cursor4, e_srcs, N_EDGES);

    // --- layer 0: transform-first GEMM, XCD-swizzled flat grid ---
    gemm_l0<<<2345, 512, 0, stream>>>(x_bf, Wt0, ebias, hB, msgbuf, D_IN);
    aggregate0<<<cdiv(N_NODES, 4), 256, 0, stream>>>(hB, msgbuf, rp4, e_srcs, inv4, hA);

    // --- layers 1..5: fused gather+mean+GEMM (wave-per-node gather) ---
    unsigned short* cur = hA;
    unsigned short* nxt = hB;
    for (int L = 1; L < N_LAYERS; ++L) {
        rgcn_layer<<<M_PAD / BM_L, 512, 0, stream>>>(
            cur, WtR + (size_t)(L - 1) * 256 * N_TOT, b_rest + (size_t)(L - 1) * 256,
            rp4, e_srcs, inv4, nxt);
        unsigned short* t = cur; cur = nxt; nxt = t;
    }
    // final h in cur

    pool_kernel<<<N_GRAPHS, 256, 0, stream>>>(cur, batch, g_feat);
    mlp_head<<<N_GRAPHS, 128, 0, stream>>>(g_feat, fc1_w, fc1_b, fc2_w, fc2_b, out);
}

// Round 7
// 1474.014 us; speedup vs baseline: 1.1822x; 1.1822x over previous
//
#include <hip/hip_runtime.h>
#include <hip/hip_bf16.h>

#define N_NODES  60000
#define N_EDGES  240000
#define N_REL    4
#define N_GRAPHS 128
#define D_IN     768
#define D_H      256
#define N_LAYERS 6
#define M_PAD    60032            // 469 * 128
#define N_TOT    1280             // L0: 256 root + 4*256 msg; also W k-stride
#define BM_L     64               // fused layer: dst rows per block
#define LDM      264              // mean tile row stride (+16B pad)

static inline int cdiv(int a, int b) { return (a + b - 1) / b; }

typedef __attribute__((ext_vector_type(8))) short short8;
typedef __attribute__((ext_vector_type(4))) float f32x4;

__device__ __forceinline__ float bf2f(unsigned short u) {
    union { unsigned int i; float f; } c; c.i = ((unsigned int)u) << 16; return c.f;
}
__device__ __forceinline__ float bflo(unsigned int u) {
    union { unsigned int i; float f; } c; c.i = u << 16; return c.f;
}
__device__ __forceinline__ float bfhi(unsigned int u) {
    union { unsigned int i; float f; } c; c.i = u & 0xffff0000u; return c.f;
}
__device__ __forceinline__ unsigned short f2bf(float f) {
    union { float f; unsigned int i; } c; c.f = f;
    unsigned int i = c.i;
    unsigned int r = (i + 0x7FFFu + ((i >> 16) & 1u)) >> 16;   // RNE
    return (unsigned short)r;
}

__device__ __forceinline__ void gload16(const void* g, void* l) {
    __builtin_amdgcn_global_load_lds((const __attribute__((address_space(1))) void*)g,
                                     (__attribute__((address_space(3))) void*)l, 16, 0, 0);
}

__device__ __forceinline__ void accum32(float4* am, uint4 v0, uint4 v1, uint4 v2, uint4 v3) {
    am[0].x += bflo(v0.x); am[0].y += bfhi(v0.x);
    am[0].z += bflo(v0.y); am[0].w += bfhi(v0.y);
    am[1].x += bflo(v0.z); am[1].y += bfhi(v0.z);
    am[1].z += bflo(v0.w); am[1].w += bfhi(v0.w);
    am[2].x += bflo(v1.x); am[2].y += bfhi(v1.x);
    am[2].z += bflo(v1.y); am[2].w += bfhi(v1.y);
    am[3].x += bflo(v1.z); am[3].y += bfhi(v1.z);
    am[3].z += bflo(v1.w); am[3].w += bfhi(v1.w);
    am[4].x += bflo(v2.x); am[4].y += bfhi(v2.x);
    am[4].z += bflo(v2.y); am[4].w += bfhi(v2.y);
    am[5].x += bflo(v2.z); am[5].y += bfhi(v2.z);
    am[5].z += bflo(v2.w); am[5].w += bfhi(v2.w);
    am[6].x += bflo(v3.x); am[6].y += bfhi(v3.x);
    am[6].z += bflo(v3.y); am[6].w += bfhi(v3.y);
    am[7].x += bflo(v3.z); am[7].y += bfhi(v3.z);
    am[7].z += bflo(v3.w); am[7].w += bfhi(v3.w);
}

// ---------------------------------------------------------------------------
// Layer-0 GEMM (transform-first): A[M_PAD,768] bf16 @ Wt0[1280,768]^T.
// Flat grid, XCD-swizzled: a row-block's 5 col-blocks share b%8 -> same XCD.
// ---------------------------------------------------------------------------
__global__ __launch_bounds__(512) void gemm_l0(
    const unsigned short* __restrict__ A,
    const unsigned short* __restrict__ Bt,
    const float* __restrict__ bias,
    unsigned short* __restrict__ out_root,
    unsigned short* __restrict__ out_msg,
    int K)
{
    __shared__ unsigned short As[128 * 32];
    __shared__ unsigned short Bs[256 * 32];

    const int tid  = threadIdx.x;
    const int wave = tid >> 6, lane = tid & 63;

    int b = blockIdx.x;
    int bm, bn;
    if (b < 2320) { int grp = b / 40, rem = b % 40; bm = (grp * 8 + (rem & 7)) * 128; bn = (rem >> 3) * 256; }
    else          { int rem = b - 2320; bm = (464 + rem % 5) * 128; bn = (rem / 5) * 256; }

    const int wm = (wave & 1) * 64, wn = (wave >> 1) * 64;

    const int lr = lane >> 2;
    const int kg = ((lane & 3) ^ ((lr ^ (lr >> 2)) & 3)) * 8;   // swizzled k-chunk
    const unsigned short* gsrc[3];
    unsigned short* ldst[3];
    #pragma unroll
    for (int j = 0; j < 3; ++j) {
        int g = wave * 3 + j;
        if (g < 8) {
            gsrc[j] = A + (size_t)(bm + g * 16 + lr) * K + kg;
            ldst[j] = As + g * 16 * 32;
        } else {
            gsrc[j] = Bt + (size_t)(bn + (g - 8) * 16 + lr) * K + kg;
            ldst[j] = Bs + (g - 8) * 16 * 32;
        }
    }

    f32x4 acc[4][4] = {};
    const int fr = lane & 15;
    const int qsw = (((lane >> 4) ^ fr ^ (fr >> 2)) & 3) * 8;

    for (int k0 = 0; k0 < K; k0 += 32) {
        gload16(gsrc[0] + k0, ldst[0]);
        gload16(gsrc[1] + k0, ldst[1]);
        gload16(gsrc[2] + k0, ldst[2]);
        __syncthreads();

        short8 a[4], bb[4];
        #pragma unroll
        for (int t = 0; t < 4; ++t) {
            a[t]  = *(const short8*)&As[(wm + t * 16 + fr) * 32 + qsw];
            bb[t] = *(const short8*)&Bs[(wn + t * 16 + fr) * 32 + qsw];
        }
        #pragma unroll
        for (int mt = 0; mt < 4; ++mt)
            #pragma unroll
            for (int nt = 0; nt < 4; ++nt)
                acc[mt][nt] = __builtin_amdgcn_mfma_f32_16x16x32_bf16(
                    a[mt], bb[nt], acc[mt][nt], 0, 0, 0);
        __syncthreads();
    }

    const bool is_root = (bn == 0);   // block-uniform
    #pragma unroll
    for (int mt = 0; mt < 4; ++mt) {
        #pragma unroll
        for (int nt = 0; nt < 4; ++nt) {
            int col = bn + wn + nt * 16 + fr;
            float bv = bias[col];
            #pragma unroll
            for (int r = 0; r < 4; ++r) {
                int row = bm + wm + mt * 16 + ((lane >> 4) << 2) + r;
                float v = acc[mt][nt][r] + bv;
                if (is_root) out_root[(size_t)row * 256 + col] = f2bf(v);
                else         out_msg[(size_t)row * 1024 + (col - 256)] = f2bf(v);
            }
        }
    }
}

// ---------------------------------------------------------------------------
// Fused RGCN mid-layer (R4 structure, measured best). Phases r in {0..3, 4=root}:
//  - gather: LANE-per-node (64 independent addresses in flight), unroll-2
//  - mean tile -> LDS (bf16), kk0 W-tile staged BEFORE gather (latency hidden)
//  - 8 MFMA K-steps, W staged to LDS per kk via global_load_lds
// ---------------------------------------------------------------------------
__global__ __launch_bounds__(512) void rgcn_layer(
    const unsigned short* __restrict__ h,     // [M_PAD, 256]
    const unsigned short* __restrict__ Wl,    // [256 out][1280 k]
    const float* __restrict__ bias,           // [256]
    const int* __restrict__ rp4,              // [4*N_NODES + 1]
    const int* __restrict__ e_srcs,           // [E] srcs sorted by (dst, rel)
    const float* __restrict__ inv4,           // [N_NODES*4]
    unsigned short* __restrict__ h_out)       // [M_PAD, 256]
{
    __shared__ unsigned short mt[BM_L * LDM];   // 33,792 B
    __shared__ unsigned short Bs[256 * 32];     // 16,384 B

    const int tid  = threadIdx.x;
    const int wave = tid >> 6, lane = tid & 63;
    const int bm = blockIdx.x * BM_L;

    const int node  = bm + lane;                 // gather: lane = node
    const int cq    = wave * 32;                 // gather: wave = 32-col slice
    const bool valid = node < N_NODES;

    const int lr = lane >> 2;
    const int kg = ((lane & 3) ^ ((lr ^ (lr >> 2)) & 3)) * 8;

    const int fr   = lane & 15;
    const int q8   = (lane >> 4) * 8;
    const int qsw = (((lane >> 4) ^ fr ^ (fr >> 2)) & 3) * 8;
    const int wcol = wave * 32;

    float4 iv = valid ? *(const float4*)&inv4[(size_t)node * 4]
                      : make_float4(1.f, 1.f, 1.f, 1.f);

    f32x4 acc[4][2] = {};

    for (int r = 0; r < 5; ++r) {
        const int rOff = r << 8;

        __syncthreads();   // previous phase's mt/Bs reads complete

        // stage Bs(kk=0) NOW -> latency hides behind gather
        {
            int g0 = wave * 2;
            gload16(Wl + (size_t)(g0 * 16 + lr) * N_TOT + rOff + kg, Bs + g0 * 512);
            gload16(Wl + (size_t)((g0 + 1) * 16 + lr) * N_TOT + rOff + kg, Bs + (g0 + 1) * 512);
        }

        // ---- gather: lane-per-node, unroll-2 independent loads ----
        float4 am[8];
        #pragma unroll
        for (int j = 0; j < 8; ++j) am[j] = make_float4(0.f, 0.f, 0.f, 0.f);

        if (r < 4) {
            if (valid) {
                int lo = rp4[(size_t)node * 4 + r];
                int hi = rp4[(size_t)node * 4 + r + 1];
                int e = lo;
                for (; e + 1 < hi; e += 2) {
                    const uint4* p0 = (const uint4*)(h + (size_t)e_srcs[e] * 256 + cq);
                    const uint4* p1 = (const uint4*)(h + (size_t)e_srcs[e + 1] * 256 + cq);
                    uint4 v0 = p0[0], v1 = p0[1], v2 = p0[2], v3 = p0[3];
                    uint4 u0 = p1[0], u1 = p1[1], u2 = p1[2], u3 = p1[3];
                    accum32(am, v0, v1, v2, v3);
                    accum32(am, u0, u1, u2, u3);
                }
                if (e < hi) {
                    const uint4* p0 = (const uint4*)(h + (size_t)e_srcs[e] * 256 + cq);
                    accum32(am, p0[0], p0[1], p0[2], p0[3]);
                }
            }
        } else {
            const uint4* p0 = (const uint4*)(h + (size_t)node * 256 + cq);
            accum32(am, p0[0], p0[1], p0[2], p0[3]);
        }
        float sc = (r == 0) ? iv.x : (r == 1) ? iv.y : (r == 2) ? iv.z
                 : (r == 3) ? iv.w : 1.f;

        // write mean tile slice (no barrier needed before: top-of-phase barrier covers)
        {
            unsigned short* dst = &mt[lane * LDM + cq];
            #pragma unroll
            for (int j = 0; j < 8; ++j) {
                ushort4 o;
                o.x = f2bf(am[j].x * sc); o.y = f2bf(am[j].y * sc);
                o.z = f2bf(am[j].z * sc); o.w = f2bf(am[j].w * sc);
                *(ushort4*)(dst + j * 4) = o;
            }
        }

        // ---- 8 MFMA K-steps; Bs staged per kk ----
        #pragma unroll 1
        for (int kk = 0; kk < 8; ++kk) {
            if (kk > 0) {
                __syncthreads();   // Bs reads of prev step done
                int g0 = wave * 2;
                gload16(Wl + (size_t)(g0 * 16 + lr) * N_TOT + rOff + kg + kk * 32,
                        Bs + g0 * 512);
                gload16(Wl + (size_t)((g0 + 1) * 16 + lr) * N_TOT + rOff + kg + kk * 32,
                        Bs + (g0 + 1) * 512);
            }
            __syncthreads();       // staging + (kk==0: mt writes) visible

            short8 a4[4], b0, b1;
            #pragma unroll
            for (int i = 0; i < 4; ++i)
                a4[i] = *(const short8*)&mt[(i * 16 + fr) * LDM + kk * 32 + q8];
            b0 = *(const short8*)&Bs[(wcol + fr) * 32 + qsw];
            b1 = *(const short8*)&Bs[(wcol + 16 + fr) * 32 + qsw];
            #pragma unroll
            for (int i = 0; i < 4; ++i) {
                acc[i][0] = __builtin_amdgcn_mfma_f32_16x16x32_bf16(a4[i], b0, acc[i][0], 0, 0, 0);
                acc[i][1] = __builtin_amdgcn_mfma_f32_16x16x32_bf16(a4[i], b1, acc[i][1], 0, 0, 0);
            }
        }
    }

    // epilogue: +bias, ReLU, bf16
    #pragma unroll
    for (int i = 0; i < 4; ++i) {
        #pragma unroll
        for (int nt = 0; nt < 2; ++nt) {
            int col = wcol + nt * 16 + fr;
            float bv = bias[col];
            #pragma unroll
            for (int rg = 0; rg < 4; ++rg) {
                int row = bm + i * 16 + ((lane >> 4) << 2) + rg;
                float v = fmaxf(acc[i][nt][rg] + bv, 0.f);
                h_out[(size_t)row * 256 + col] = f2bf(v);
            }
        }
    }
}

// ---------------------------------------------------------------------------
// Prep kernels
// ---------------------------------------------------------------------------
__global__ void convert_x(const float* __restrict__ x, unsigned short* __restrict__ xb) {
    size_t i = ((size_t)blockIdx.x * 256 + threadIdx.x) * 4;
    if (i >= (size_t)M_PAD * D_IN) return;
    ushort4 o;
    if (i < (size_t)N_NODES * D_IN) {
        float4 v = *(const float4*)&x[i];
        o.x = f2bf(v.x); o.y = f2bf(v.y); o.z = f2bf(v.z); o.w = f2bf(v.w);
    } else {
        o.x = o.y = o.z = o.w = 0;
    }
    *(ushort4*)&xb[i] = o;
}

__global__ void pack_w0(const float* __restrict__ root0, const float* __restrict__ w0,
                        const float* __restrict__ b0, float* __restrict__ eb,
                        unsigned short* __restrict__ Wt0) {
    int idx = blockIdx.x * 256 + threadIdx.x;            // Wt0[n][k], [1280 x 768]
    if (idx < N_TOT) eb[idx] = (idx < 256) ? b0[idx] : 0.f;   // folded bias build
    if (idx >= N_TOT * D_IN) return;
    int k = idx % D_IN, n = idx / D_IN;
    float v = (n < 256) ? root0[k * 256 + n]
                        : w0[(((n >> 8) - 1) * D_IN + k) * 256 + (n & 255)];
    Wt0[idx] = f2bf(v);
}

// WtR[l][n][k]: k<1024 -> w_rest[l][k>>8][k&255][n]; k>=1024 -> root_rest[l][k-1024][n]
__global__ void pack_wr(const float* __restrict__ root_rest, const float* __restrict__ w_rest,
                        unsigned short* __restrict__ WtR) {
    int idx = blockIdx.x * 256 + threadIdx.x;
    if (idx >= 5 * 256 * N_TOT) return;
    int k = idx % N_TOT; int t = idx / N_TOT; int n = t & 255; int l = t >> 8;
    float v = (k < 1024)
        ? w_rest[(((l * 4 + (k >> 8)) * 256) + (k & 255)) * 256 + n]
        : root_rest[(l * 256 + (k - 1024)) * 256 + n];
    WtR[idx] = f2bf(v);
}

// ---------------------------------------------------------------------------
// (dst, rel)-sorted CSR over 4*N segments
// ---------------------------------------------------------------------------
__global__ void deg4_count(const int* __restrict__ dst, const int* __restrict__ rel,
                           int* __restrict__ deg4, int E) {
    int e = blockIdx.x * 256 + threadIdx.x;
    if (e < E) atomicAdd(&deg4[dst[e] * 4 + rel[e]], 1);
}

__global__ __launch_bounds__(256) void block_sum(const int* __restrict__ deg,
                                                 int* __restrict__ bsum, int n) {
    __shared__ int s[256];
    int i = blockIdx.x * 256 + threadIdx.x;
    s[threadIdx.x] = (i < n) ? deg[i] : 0;
    __syncthreads();
    for (int o = 128; o > 0; o >>= 1) {
        if (threadIdx.x < o) s[threadIdx.x] += s[threadIdx.x + o];
        __syncthreads();
    }
    if (threadIdx.x == 0) bsum[blockIdx.x] = s[0];
}

__global__ __launch_bounds__(1024) void scan_bsum(const int* __restrict__ bsum,
                                                  int* __restrict__ boff, int nb) {
    __shared__ int s[1024];
    int t = threadIdx.x;
    int v0 = (t < nb) ? bsum[t] : 0;
    s[t] = v0;
    __syncthreads();
    for (int o = 1; o < 1024; o <<= 1) {
        int v = (t >= o) ? s[t - o] : 0;
        __syncthreads();
        s[t] += v;
        __syncthreads();
    }
    if (t < nb) boff[t] = s[t] - v0;   // exclusive
}

// also emits inv4 (folded invert4)
__global__ __launch_bounds__(256) void block_scan_write(
    const int* __restrict__ deg, const int* __restrict__ boff,
    int* __restrict__ row_ptr, int* __restrict__ cursor,
    float* __restrict__ inv4, int n, int total) {
    __shared__ int s[256];
    int t = threadIdx.x;
    int i = blockIdx.x * 256 + t;
    int v = (i < n) ? deg[i] : 0;
    s[t] = v;
    __syncthreads();
    for (int o = 1; o < 256; o <<= 1) {
        int u = (t >= o) ? s[t - o] : 0;
        __syncthreads();
        s[t] += u;
        __syncthreads();
    }
    int excl = s[t] - v + boff[blockIdx.x];
    if (i < n) {
        row_ptr[i] = excl; cursor[i] = excl;
        inv4[i] = 1.0f / (float)max(v, 1);
    }
    if (blockIdx.x == 0 && t == 0) row_ptr[n] = total;
}

// emits e_srcs (for fused gather), eoff = src*4+rel and ew = inv weight (for agg0)
__global__ void place_edges4(const int* __restrict__ dst, const int* __restrict__ src,
                             const int* __restrict__ rel, const float* __restrict__ inv4,
                             int* __restrict__ cursor,
                             int* __restrict__ e_srcs, int* __restrict__ eoff,
                             float* __restrict__ ew, int E) {
    int e = blockIdx.x * 256 + threadIdx.x;
    if (e < E) {
        int d = dst[e], r = rel[e], s = src[e];
        int seg = d * 4 + r;
        int p = atomicAdd(&cursor[seg], 1);
        e_srcs[p] = s;
        eoff[p]   = s * 4 + r;
        ew[p]     = inv4[seg];
    }
}

// ---------------------------------------------------------------------------
// Layer-0 aggregate: h0 = relu(root[n] + sum_e ew[e] * msg[eoff[e]])
// Single merged edge loop, unroll-4 INDEPENDENT coalesced 512B loads.
// ---------------------------------------------------------------------------
__global__ __launch_bounds__(256) void aggregate0(
    const unsigned short* __restrict__ rootb,   // [M_PAD,256] (bias folded)
    const unsigned short* __restrict__ msg,     // [M_PAD,1024]
    const int* __restrict__ rp4, const int* __restrict__ eoff,
    const float* __restrict__ ew,
    unsigned short* __restrict__ h_out)         // [M_PAD,256]
{
    int node = blockIdx.x * 4 + (threadIdx.x >> 6);
    if (node >= N_NODES) return;
    int lane = threadIdx.x & 63;
    const int cc = lane * 4;

    ushort4 rt = *(const ushort4*)&rootb[(size_t)node * 256 + cc];
    float4 acc = make_float4(bf2f(rt.x), bf2f(rt.y), bf2f(rt.z), bf2f(rt.w));

    int lo = rp4[(size_t)node * 4];
    int hi = rp4[(size_t)node * 4 + 4];
    int e = lo;
    for (; e + 3 < hi; e += 4) {
        int o0 = eoff[e], o1 = eoff[e + 1], o2 = eoff[e + 2], o3 = eoff[e + 3];
        float w0 = ew[e], w1 = ew[e + 1], w2 = ew[e + 2], w3 = ew[e + 3];
        ushort4 m0 = *(const ushort4*)&msg[(size_t)o0 * 256 + cc];
        ushort4 m1 = *(const ushort4*)&msg[(size_t)o1 * 256 + cc];
        ushort4 m2 = *(const ushort4*)&msg[(size_t)o2 * 256 + cc];
        ushort4 m3 = *(const ushort4*)&msg[(size_t)o3 * 256 + cc];
        acc.x += w0 * bf2f(m0.x) + w1 * bf2f(m1.x) + w2 * bf2f(m2.x) + w3 * bf2f(m3.x);
        acc.y += w0 * bf2f(m0.y) + w1 * bf2f(m1.y) + w2 * bf2f(m2.y) + w3 * bf2f(m3.y);
        acc.z += w0 * bf2f(m0.z) + w1 * bf2f(m1.z) + w2 * bf2f(m2.z) + w3 * bf2f(m3.z);
        acc.w += w0 * bf2f(m0.w) + w1 * bf2f(m1.w) + w2 * bf2f(m2.w) + w3 * bf2f(m3.w);
    }
    for (; e < hi; ++e) {
        int o0 = eoff[e];
        float w0 = ew[e];
        ushort4 m0 = *(const ushort4*)&msg[(size_t)o0 * 256 + cc];
        acc.x += w0 * bf2f(m0.x); acc.y += w0 * bf2f(m0.y);
        acc.z += w0 * bf2f(m0.z); acc.w += w0 * bf2f(m0.w);
    }
    ushort4 o;
    o.x = f2bf(fmaxf(acc.x, 0.f));
    o.y = f2bf(fmaxf(acc.y, 0.f));
    o.z = f2bf(fmaxf(acc.z, 0.f));
    o.w = f2bf(fmaxf(acc.w, 0.f));
    *(ushort4*)&h_out[(size_t)node * 256 + cc] = o;
}

// ---------------------------------------------------------------------------
// Pooling + MLP head
// ---------------------------------------------------------------------------
__global__ __launch_bounds__(256) void pool_kernel(
    const unsigned short* __restrict__ h, const int* __restrict__ batch,
    float* __restrict__ g_feat)
{
    int g = blockIdx.x;
    int t = threadIdx.x;
    __shared__ int s_lo, s_hi;
    if (t == 0) {
        int lo = 0, hi = N_NODES;
        while (lo < hi) { int m = (lo + hi) >> 1; if (batch[m] < g) lo = m + 1; else hi = m; }
        s_lo = lo;
        int lo2 = lo, hi2 = N_NODES;
        while (lo2 < hi2) { int m = (lo2 + hi2) >> 1; if (batch[m] < g + 1) lo2 = m + 1; else hi2 = m; }
        s_hi = lo2;
    }
    __syncthreads();
    int lo = s_lo, hi = s_hi;
    float sum = 0.f, mx = 0.f;   // post-ReLU
    for (int n = lo; n < hi; ++n) {
        float v = bf2f(h[(size_t)n * 256 + t]);
        sum += v;
        mx = fmaxf(mx, v);
    }
    float cnt = (float)(hi - lo);
    g_feat[g * 512 + t]       = sum / fmaxf(cnt, 1.0f);
    g_feat[g * 512 + 256 + t] = (cnt > 0.f) ? mx : 0.f;
}

__global__ __launch_bounds__(128) void mlp_head(
    const float* __restrict__ g_feat,
    const float* __restrict__ fc1_w, const float* __restrict__ fc1_b,
    const float* __restrict__ fc2_w, const float* __restrict__ fc2_b,
    float* __restrict__ out)
{
    __shared__ float gf[512];
    __shared__ float partial[2];
    int g = blockIdx.x, t = threadIdx.x;
    for (int i = t; i < 512; i += 128) gf[i] = g_feat[g * 512 + i];
    __syncthreads();
    float acc = fc1_b[t];
    for (int i = 0; i < 512; ++i) acc += gf[i] * fc1_w[i * 128 + t];
    float h1 = fmaxf(acc, 0.f);
    float v = h1 * fc2_w[t];
    #pragma unroll
    for (int off = 32; off > 0; off >>= 1) v += __shfl_down(v, off);
    if ((t & 63) == 0) partial[t >> 6] = v;
    __syncthreads();
    if (t == 0) {
        float s = partial[0] + partial[1] + fc2_b[0];
        out[g] = 1.0f / (1.0f + expf(-s));
    }
}

// ---------------------------------------------------------------------------
// Launch
// ---------------------------------------------------------------------------
extern "C" void kernel_launch(void* const* d_in, const int* in_sizes, int n_in,
                              void* d_out, int out_size, void* d_ws, size_t ws_size,
                              hipStream_t stream) {
    const float* x          = (const float*)d_in[0];
    const int*   edge_index = (const int*)d_in[1];
    const int*   edge_attr  = (const int*)d_in[2];
    const int*   batch      = (const int*)d_in[3];
    const float* w0         = (const float*)d_in[4];
    const float* root0      = (const float*)d_in[5];
    const float* b0         = (const float*)d_in[6];
    const float* w_rest     = (const float*)d_in[7];
    const float* root_rest  = (const float*)d_in[8];
    const float* b_rest     = (const float*)d_in[9];
    const float* fc1_w      = (const float*)d_in[10];
    const float* fc1_b      = (const float*)d_in[11];
    const float* fc2_w      = (const float*)d_in[12];
    const float* fc2_b      = (const float*)d_in[13];
    float* out = (float*)d_out;

    const int* e_src = edge_index;
    const int* e_dst = edge_index + N_EDGES;

    char* p = (char*)d_ws;
    auto alloc = [&](size_t bytes) { char* q = p; p += (bytes + 255) & ~(size_t)255; return q; };
    unsigned short* x_bf   = (unsigned short*)alloc((size_t)M_PAD * D_IN * 2);   // 92 MB
    unsigned short* msgbuf = (unsigned short*)alloc((size_t)M_PAD * 1024 * 2);   // 123 MB
    unsigned short* hA     = (unsigned short*)alloc((size_t)M_PAD * 256 * 2);    // 31 MB
    unsigned short* hB     = (unsigned short*)alloc((size_t)M_PAD * 256 * 2);    // 31 MB
    unsigned short* Wt0    = (unsigned short*)alloc((size_t)N_TOT * D_IN * 2);
    unsigned short* WtR    = (unsigned short*)alloc((size_t)5 * 256 * N_TOT * 2);
    float*          ebias  = (float*)alloc(N_TOT * 4);
    float*          inv4   = (float*)alloc((size_t)N_NODES * 4 * 4);
    float*          g_feat = (float*)alloc((size_t)N_GRAPHS * 512 * 4);
    int*            deg4   = (int*)alloc((size_t)N_NODES * 4 * 4);
    int*            rp4    = (int*)alloc(((size_t)N_NODES * 4 + 1) * 4);
    int*            cursor4= (int*)alloc((size_t)N_NODES * 4 * 4);
    int*            bsum   = (int*)alloc(1024 * 4);
    int*            boff   = (int*)alloc(1024 * 4);
    int*            e_srcs = (int*)alloc((size_t)N_EDGES * 4);
    int*            eoff   = (int*)alloc((size_t)N_EDGES * 4);
    float*          ew     = (float*)alloc((size_t)N_EDGES * 4);

    const int n4 = N_NODES * 4;                 // 240000
    const int nscan4 = cdiv(n4, 256);           // 938

    // --- prep ---
    hipMemsetAsync(deg4, 0, (size_t)n4 * 4, stream);
    convert_x<<<cdiv(M_PAD * D_IN / 4, 256), 256, 0, stream>>>(x, x_bf);
    pack_w0<<<cdiv(N_TOT * D_IN, 256), 256, 0, stream>>>(root0, w0, b0, ebias, Wt0);
    pack_wr<<<cdiv(5 * 256 * N_TOT, 256), 256, 0, stream>>>(root_rest, w_rest, WtR);
    deg4_count<<<cdiv(N_EDGES, 256), 256, 0, stream>>>(e_dst, edge_attr, deg4, N_EDGES);
    block_sum<<<nscan4, 256, 0, stream>>>(deg4, bsum, n4);
    scan_bsum<<<1, 1024, 0, stream>>>(bsum, boff, nscan4);
    block_scan_write<<<nscan4, 256, 0, stream>>>(deg4, boff, rp4, cursor4, inv4, n4, N_EDGES);
    place_edges4<<<cdiv(N_EDGES, 256), 256, 0, stream>>>(e_dst, e_src, edge_attr, inv4,
                                                         cursor4, e_srcs, eoff, ew, N_EDGES);

    // --- layer 0: transform-first GEMM, XCD-swizzled flat grid ---
    gemm_l0<<<2345, 512, 0, stream>>>(x_bf, Wt0, ebias, hB, msgbuf, D_IN);
    aggregate0<<<cdiv(N_NODES, 4), 256, 0, stream>>>(hB, msgbuf, rp4, eoff, ew, hA);

    // --- layers 1..5: fused gather+mean+GEMM (R4 structure) ---
    unsigned short* cur = hA;
    unsigned short* nxt = hB;
    for (int L = 1; L < N_LAYERS; ++L) {
        rgcn_layer<<<M_PAD / BM_L, 512, 0, stream>>>(
            cur, WtR + (size_t)(L - 1) * 256 * N_TOT, b_rest + (size_t)(L - 1) * 256,
            rp4, e_srcs, inv4, nxt);
        unsigned short* t = cur; cur = nxt; nxt = t;
    }
    // final h in cur

    pool_kernel<<<N_GRAPHS, 256, 0, stream>>>(cur, batch, g_feat);
    mlp_head<<<N_GRAPHS, 128, 0, stream>>>(g_feat, fc1_w, fc1_b, fc2_w, fc2_b, out);
}

// Round 8
// 1467.752 us; speedup vs baseline: 1.1873x; 1.0043x over previous
//
#include <hip/hip_runtime.h>
#include <hip/hip_bf16.h>

#define N_NODES  60000
#define N_EDGES  240000
#define N_REL    4
#define N_GRAPHS 128
#define D_IN     768
#define D_H      256
#define N_LAYERS 6
#define M_PAD    60032            // 469 * 128
#define N_TOT    1280             // L0: 256 root + 4*256 msg; also W k-stride
#define BM_L     64               // fused layer: dst rows per block
#define LDM      264              // mean tile row stride (+16B pad)

static inline int cdiv(int a, int b) { return (a + b - 1) / b; }

typedef __attribute__((ext_vector_type(8))) short short8;
typedef __attribute__((ext_vector_type(4))) float f32x4;

__device__ __forceinline__ float bf2f(unsigned short u) {
    union { unsigned int i; float f; } c; c.i = ((unsigned int)u) << 16; return c.f;
}
__device__ __forceinline__ float bflo(unsigned int u) {
    union { unsigned int i; float f; } c; c.i = u << 16; return c.f;
}
__device__ __forceinline__ float bfhi(unsigned int u) {
    union { unsigned int i; float f; } c; c.i = u & 0xffff0000u; return c.f;
}
__device__ __forceinline__ unsigned short f2bf(float f) {
    union { float f; unsigned int i; } c; c.f = f;
    unsigned int i = c.i;
    unsigned int r = (i + 0x7FFFu + ((i >> 16) & 1u)) >> 16;   // RNE
    return (unsigned short)r;
}

__device__ __forceinline__ void gload16(const void* g, void* l) {
    __builtin_amdgcn_global_load_lds((const __attribute__((address_space(1))) void*)g,
                                     (__attribute__((address_space(3))) void*)l, 16, 0, 0);
}

__device__ __forceinline__ void accum32(float4* am, uint4 v0, uint4 v1, uint4 v2, uint4 v3) {
    am[0].x += bflo(v0.x); am[0].y += bfhi(v0.x);
    am[0].z += bflo(v0.y); am[0].w += bfhi(v0.y);
    am[1].x += bflo(v0.z); am[1].y += bfhi(v0.z);
    am[1].z += bflo(v0.w); am[1].w += bfhi(v0.w);
    am[2].x += bflo(v1.x); am[2].y += bfhi(v1.x);
    am[2].z += bflo(v1.y); am[2].w += bfhi(v1.y);
    am[3].x += bflo(v1.z); am[3].y += bfhi(v1.z);
    am[3].z += bflo(v1.w); am[3].w += bfhi(v1.w);
    am[4].x += bflo(v2.x); am[4].y += bfhi(v2.x);
    am[4].z += bflo(v2.y); am[4].w += bfhi(v2.y);
    am[5].x += bflo(v2.z); am[5].y += bfhi(v2.z);
    am[5].z += bflo(v2.w); am[5].w += bfhi(v2.w);
    am[6].x += bflo(v3.x); am[6].y += bfhi(v3.x);
    am[6].z += bflo(v3.y); am[6].w += bfhi(v3.y);
    am[7].x += bflo(v3.z); am[7].y += bfhi(v3.z);
    am[7].z += bflo(v3.w); am[7].w += bfhi(v3.w);
}

// ---------------------------------------------------------------------------
// Layer-0 GEMM (transform-first): A[M_PAD,768] bf16 @ Wt0[1280,768]^T.
// Flat grid, XCD-swizzled: a row-block's 5 col-blocks share b%8 -> same XCD
// (measured: FETCH 264 -> 87 MB).
// ---------------------------------------------------------------------------
__global__ __launch_bounds__(512) void gemm_l0(
    const unsigned short* __restrict__ A,
    const unsigned short* __restrict__ Bt,
    const float* __restrict__ bias,
    unsigned short* __restrict__ out_root,
    unsigned short* __restrict__ out_msg,
    int K)
{
    __shared__ unsigned short As[128 * 32];
    __shared__ unsigned short Bs[256 * 32];

    const int tid  = threadIdx.x;
    const int wave = tid >> 6, lane = tid & 63;

    int b = blockIdx.x;
    int bm, bn;
    if (b < 2320) { int grp = b / 40, rem = b % 40; bm = (grp * 8 + (rem & 7)) * 128; bn = (rem >> 3) * 256; }
    else          { int rem = b - 2320; bm = (464 + rem % 5) * 128; bn = (rem / 5) * 256; }

    const int wm = (wave & 1) * 64, wn = (wave >> 1) * 64;

    const int lr = lane >> 2;
    const int kg = ((lane & 3) ^ ((lr ^ (lr >> 2)) & 3)) * 8;   // swizzled k-chunk
    const unsigned short* gsrc[3];
    unsigned short* ldst[3];
    #pragma unroll
    for (int j = 0; j < 3; ++j) {
        int g = wave * 3 + j;
        if (g < 8) {
            gsrc[j] = A + (size_t)(bm + g * 16 + lr) * K + kg;
            ldst[j] = As + g * 16 * 32;
        } else {
            gsrc[j] = Bt + (size_t)(bn + (g - 8) * 16 + lr) * K + kg;
            ldst[j] = Bs + (g - 8) * 16 * 32;
        }
    }

    f32x4 acc[4][4] = {};
    const int fr = lane & 15;
    const int qsw = (((lane >> 4) ^ fr ^ (fr >> 2)) & 3) * 8;

    for (int k0 = 0; k0 < K; k0 += 32) {
        gload16(gsrc[0] + k0, ldst[0]);
        gload16(gsrc[1] + k0, ldst[1]);
        gload16(gsrc[2] + k0, ldst[2]);
        __syncthreads();

        short8 a[4], bb[4];
        #pragma unroll
        for (int t = 0; t < 4; ++t) {
            a[t]  = *(const short8*)&As[(wm + t * 16 + fr) * 32 + qsw];
            bb[t] = *(const short8*)&Bs[(wn + t * 16 + fr) * 32 + qsw];
        }
        #pragma unroll
        for (int mt = 0; mt < 4; ++mt)
            #pragma unroll
            for (int nt = 0; nt < 4; ++nt)
                acc[mt][nt] = __builtin_amdgcn_mfma_f32_16x16x32_bf16(
                    a[mt], bb[nt], acc[mt][nt], 0, 0, 0);
        __syncthreads();
    }

    const bool is_root = (bn == 0);   // block-uniform
    #pragma unroll
    for (int mt = 0; mt < 4; ++mt) {
        #pragma unroll
        for (int nt = 0; nt < 4; ++nt) {
            int col = bn + wn + nt * 16 + fr;
            float bv = bias[col];
            #pragma unroll
            for (int r = 0; r < 4; ++r) {
                int row = bm + wm + mt * 16 + ((lane >> 4) << 2) + r;
                float v = acc[mt][nt][r] + bv;
                if (is_root) out_root[(size_t)row * 256 + col] = f2bf(v);
                else         out_msg[(size_t)row * 1024 + (col - 256)] = f2bf(v);
            }
        }
    }
}

// ---------------------------------------------------------------------------
// Fused RGCN mid-layer — round-4 structure verbatim (measured best ~120us):
// lane-per-node gather, mean tile -> LDS, W staged through LDS per kk.
// ---------------------------------------------------------------------------
__global__ __launch_bounds__(512) void rgcn_layer(
    const unsigned short* __restrict__ h,     // [M_PAD, 256]
    const unsigned short* __restrict__ Wl,    // [256 out][1280 k]
    const float* __restrict__ bias,           // [256]
    const int* __restrict__ rp4,              // [4*N_NODES + 1]
    const int* __restrict__ e_srcs,           // [E] srcs sorted by (dst, rel)
    const float* __restrict__ inv4,           // [N_NODES*4]
    unsigned short* __restrict__ h_out)       // [M_PAD, 256]
{
    __shared__ unsigned short mt[BM_L * LDM];   // 33,792 B
    __shared__ unsigned short Bs[256 * 32];     // 16,384 B

    const int tid  = threadIdx.x;
    const int wave = tid >> 6, lane = tid & 63;
    const int bm = blockIdx.x * BM_L;

    const int node  = bm + lane;                 // gather: lane = node
    const int cq    = wave * 32;                 // gather: wave = 32-col slice
    const bool valid = node < N_NODES;

    const int lr = lane >> 2;
    const int kg = ((lane & 3) ^ ((lr ^ (lr >> 2)) & 3)) * 8;

    const int fr  = lane & 15;
    const int q8  = (lane >> 4) * 8;
    const int qsw = (((lane >> 4) ^ fr ^ (fr >> 2)) & 3) * 8;
    const int wcol = wave * 32;

    float4 iv = valid ? *(const float4*)&inv4[(size_t)node * 4]
                      : make_float4(1.f, 1.f, 1.f, 1.f);

    f32x4 acc[4][2] = {};

    for (int r = 0; r < 5; ++r) {
        float4 am[8];
        #pragma unroll
        for (int j = 0; j < 8; ++j) am[j] = make_float4(0.f, 0.f, 0.f, 0.f);

        if (r < 4) {
            if (valid) {
                int lo = rp4[(size_t)node * 4 + r];
                int hi = rp4[(size_t)node * 4 + r + 1];
                int e = lo;
                for (; e + 1 < hi; e += 2) {
                    const uint4* p0 = (const uint4*)(h + (size_t)e_srcs[e] * 256 + cq);
                    const uint4* p1 = (const uint4*)(h + (size_t)e_srcs[e + 1] * 256 + cq);
                    uint4 v0 = p0[0], v1 = p0[1], v2 = p0[2], v3 = p0[3];
                    uint4 u0 = p1[0], u1 = p1[1], u2 = p1[2], u3 = p1[3];
                    accum32(am, v0, v1, v2, v3);
                    accum32(am, u0, u1, u2, u3);
                }
                if (e < hi) {
                    const uint4* p0 = (const uint4*)(h + (size_t)e_srcs[e] * 256 + cq);
                    accum32(am, p0[0], p0[1], p0[2], p0[3]);
                }
            }
        } else {
            const uint4* p0 = (const uint4*)(h + (size_t)node * 256 + cq);
            accum32(am, p0[0], p0[1], p0[2], p0[3]);
        }
        float sc = (r == 0) ? iv.x : (r == 1) ? iv.y : (r == 2) ? iv.z
                 : (r == 3) ? iv.w : 1.f;

        __syncthreads();   // previous phase's mt reads complete
        {
            unsigned short* dst = &mt[lane * LDM + cq];
            #pragma unroll
            for (int j = 0; j < 8; ++j) {
                ushort4 o;
                o.x = f2bf(am[j].x * sc); o.y = f2bf(am[j].y * sc);
                o.z = f2bf(am[j].z * sc); o.w = f2bf(am[j].w * sc);
                *(ushort4*)(dst + j * 4) = o;
            }
        }

        // ---- 8 MFMA K-steps against W slice (k offset r*256) ----
        const int rOff = r << 8;
        #pragma unroll 1
        for (int kk = 0; kk < 8; ++kk) {
            if (kk > 0) __syncthreads();      // Bs reads of prev step done
            {
                int g0 = wave * 2;
                gload16(Wl + (size_t)(g0 * 16 + lr) * N_TOT + rOff + kg + kk * 32,
                        Bs + g0 * 512);
                gload16(Wl + (size_t)((g0 + 1) * 16 + lr) * N_TOT + rOff + kg + kk * 32,
                        Bs + (g0 + 1) * 512);
            }
            __syncthreads();                  // staging + (kk==0: mt writes) visible

            short8 a4[4], b0, b1;
            #pragma unroll
            for (int i = 0; i < 4; ++i)
                a4[i] = *(const short8*)&mt[(i * 16 + fr) * LDM + kk * 32 + q8];
            b0 = *(const short8*)&Bs[(wcol + fr) * 32 + qsw];
            b1 = *(const short8*)&Bs[(wcol + 16 + fr) * 32 + qsw];
            #pragma unroll
            for (int i = 0; i < 4; ++i) {
                acc[i][0] = __builtin_amdgcn_mfma_f32_16x16x32_bf16(a4[i], b0, acc[i][0], 0, 0, 0);
                acc[i][1] = __builtin_amdgcn_mfma_f32_16x16x32_bf16(a4[i], b1, acc[i][1], 0, 0, 0);
            }
        }
        __syncthreads();   // mt/Bs reads done before next phase rewrites
    }

    // epilogue: +bias, ReLU, bf16
    #pragma unroll
    for (int i = 0; i < 4; ++i) {
        #pragma unroll
        for (int nt = 0; nt < 2; ++nt) {
            int col = wcol + nt * 16 + fr;
            float bv = bias[col];
            #pragma unroll
            for (int rg = 0; rg < 4; ++rg) {
                int row = bm + i * 16 + ((lane >> 4) << 2) + rg;
                float v = fmaxf(acc[i][nt][rg] + bv, 0.f);
                h_out[(size_t)row * 256 + col] = f2bf(v);
            }
        }
    }
}

// ---------------------------------------------------------------------------
// Prep kernels
// ---------------------------------------------------------------------------
__global__ void convert_x(const float* __restrict__ x, unsigned short* __restrict__ xb) {
    size_t i = ((size_t)blockIdx.x * 256 + threadIdx.x) * 4;
    if (i >= (size_t)M_PAD * D_IN) return;
    ushort4 o;
    if (i < (size_t)N_NODES * D_IN) {
        float4 v = *(const float4*)&x[i];
        o.x = f2bf(v.x); o.y = f2bf(v.y); o.z = f2bf(v.z); o.w = f2bf(v.w);
    } else {
        o.x = o.y = o.z = o.w = 0;
    }
    *(ushort4*)&xb[i] = o;
}

// Tiled transpose-cast: Wt0[(i*256+n)*768 + k] = src_i[k*256 + n], coalesced
// both sides via 32x32 LDS tile. i in 0..4 (root0, w0[0..3]).
__global__ __launch_bounds__(256) void pack_w0_t(
    const float* __restrict__ root0, const float* __restrict__ w0,
    unsigned short* __restrict__ Wt0)
{
    __shared__ float t[32][33];
    int b = blockIdx.x;                 // 5 * 24 * 8 = 960
    int i  = b / 192;
    int rem = b % 192;
    int kb = (rem / 8) * 32;
    int nb = (rem % 8) * 32;
    const float* S = (i == 0) ? root0 : w0 + (size_t)(i - 1) * D_IN * 256;
    int tx = threadIdx.x & 31, ty = threadIdx.x >> 5;   // 32 x 8
    #pragma unroll
    for (int j = 0; j < 4; ++j)
        t[ty + j * 8][tx] = S[(size_t)(kb + ty + j * 8) * 256 + nb + tx];
    __syncthreads();
    #pragma unroll
    for (int j = 0; j < 4; ++j)
        Wt0[(size_t)(i * 256 + nb + ty + j * 8) * D_IN + kb + tx] = f2bf(t[tx][ty + j * 8]);
}

// WtR[(l*256+n)*1280 + j*256 + k2] = (j<4 ? w_rest[l][j] : root_rest[l])[k2*256+n]
__global__ __launch_bounds__(256) void pack_wr_t(
    const float* __restrict__ root_rest, const float* __restrict__ w_rest,
    unsigned short* __restrict__ WtR)
{
    __shared__ float t[32][33];
    int b = blockIdx.x;                 // 25 * 8 * 8 = 1600
    int m = b / 64;                     // matrix id: l*5 + j
    int rem = b % 64;
    int kb = (rem / 8) * 32;
    int nb = (rem % 8) * 32;
    int l = m / 5, j = m % 5;
    const float* S = (j < 4) ? w_rest + (size_t)(l * 4 + j) * 256 * 256
                             : root_rest + (size_t)l * 256 * 256;
    int tx = threadIdx.x & 31, ty = threadIdx.x >> 5;
    #pragma unroll
    for (int jj = 0; jj < 4; ++jj)
        t[ty + jj * 8][tx] = S[(size_t)(kb + ty + jj * 8) * 256 + nb + tx];
    __syncthreads();
    #pragma unroll
    for (int jj = 0; jj < 4; ++jj)
        WtR[(size_t)(l * 256 + nb + ty + jj * 8) * N_TOT + j * 256 + kb + tx] =
            f2bf(t[tx][ty + jj * 8]);
}

__global__ void build_bias(const float* __restrict__ b0, float* __restrict__ eb) {
    int i = blockIdx.x * 256 + threadIdx.x;
    if (i < N_TOT) eb[i] = (i < 256) ? b0[i] : 0.f;
}

// ---------------------------------------------------------------------------
// (dst, rel)-sorted CSR over 4*N segments
// ---------------------------------------------------------------------------
__global__ void deg4_count(const int* __restrict__ dst, const int* __restrict__ rel,
                           int* __restrict__ deg4, int E) {
    int e = blockIdx.x * 256 + threadIdx.x;
    if (e < E) atomicAdd(&deg4[dst[e] * 4 + rel[e]], 1);
}

__global__ void invert4(const int* __restrict__ deg4, float* __restrict__ inv4, int n) {
    int i = blockIdx.x * 256 + threadIdx.x;
    if (i < n) inv4[i] = 1.0f / (float)max(deg4[i], 1);
}

__global__ __launch_bounds__(256) void block_sum(const int* __restrict__ deg,
                                                 int* __restrict__ bsum, int n) {
    __shared__ int s[256];
    int i = blockIdx.x * 256 + threadIdx.x;
    s[threadIdx.x] = (i < n) ? deg[i] : 0;
    __syncthreads();
    for (int o = 128; o > 0; o >>= 1) {
        if (threadIdx.x < o) s[threadIdx.x] += s[threadIdx.x + o];
        __syncthreads();
    }
    if (threadIdx.x == 0) bsum[blockIdx.x] = s[0];
}

__global__ __launch_bounds__(1024) void scan_bsum(const int* __restrict__ bsum,
                                                  int* __restrict__ boff, int nb) {
    __shared__ int s[1024];
    int t = threadIdx.x;
    int v0 = (t < nb) ? bsum[t] : 0;
    s[t] = v0;
    __syncthreads();
    for (int o = 1; o < 1024; o <<= 1) {
        int v = (t >= o) ? s[t - o] : 0;
        __syncthreads();
        s[t] += v;
        __syncthreads();
    }
    if (t < nb) boff[t] = s[t] - v0;   // exclusive
}

__global__ __launch_bounds__(256) void block_scan_write(
    const int* __restrict__ deg, const int* __restrict__ boff,
    int* __restrict__ row_ptr, int* __restrict__ cursor, int n, int total) {
    __shared__ int s[256];
    int t = threadIdx.x;
    int i = blockIdx.x * 256 + t;
    int v = (i < n) ? deg[i] : 0;
    s[t] = v;
    __syncthreads();
    for (int o = 1; o < 256; o <<= 1) {
        int u = (t >= o) ? s[t - o] : 0;
        __syncthreads();
        s[t] += u;
        __syncthreads();
    }
    int excl = s[t] - v + boff[blockIdx.x];
    if (i < n) { row_ptr[i] = excl; cursor[i] = excl; }
    if (blockIdx.x == 0 && t == 0) row_ptr[n] = total;
}

__global__ void place_edges4(const int* __restrict__ dst, const int* __restrict__ src,
                             const int* __restrict__ rel, int* __restrict__ cursor,
                             int* __restrict__ e_srcs, int E) {
    int e = blockIdx.x * 256 + threadIdx.x;
    if (e < E) {
        int p = atomicAdd(&cursor[dst[e] * 4 + rel[e]], 1);
        e_srcs[p] = src[e];
    }
}

// ---------------------------------------------------------------------------
// Layer-0 aggregate: h0 = relu(root[n] + sum_r inv_r * sum_e msg[src, r])
// ---------------------------------------------------------------------------
__global__ __launch_bounds__(256) void aggregate0(
    const unsigned short* __restrict__ rootb,   // [M_PAD,256]
    const unsigned short* __restrict__ msg,     // [M_PAD,1024]
    const int* __restrict__ rp4, const int* __restrict__ e_srcs,
    const float* __restrict__ inv4,
    unsigned short* __restrict__ h_out)         // [M_PAD,256]
{
    int node = blockIdx.x * 4 + (threadIdx.x >> 6);
    if (node >= N_NODES) return;
    int lane = threadIdx.x & 63;
    float4 iv = *(const float4*)&inv4[(size_t)node * 4];

    ushort4 rt = *(const ushort4*)&rootb[(size_t)node * 256 + lane * 4];
    float4 acc = make_float4(bf2f(rt.x), bf2f(rt.y), bf2f(rt.z), bf2f(rt.w));

    #pragma unroll
    for (int r = 0; r < 4; ++r) {
        int lo = rp4[(size_t)node * 4 + r], hi = rp4[(size_t)node * 4 + r + 1];
        float f = (r == 0) ? iv.x : (r == 1) ? iv.y : (r == 2) ? iv.z : iv.w;
        float4 s4 = make_float4(0, 0, 0, 0);
        for (int e = lo; e < hi; ++e) {
            int s = e_srcs[e];
            ushort4 m = *(const ushort4*)&msg[(size_t)s * 1024 + (r << 8) + lane * 4];
            s4.x += bf2f(m.x); s4.y += bf2f(m.y);
            s4.z += bf2f(m.z); s4.w += bf2f(m.w);
        }
        acc.x += s4.x * f; acc.y += s4.y * f;
        acc.z += s4.z * f; acc.w += s4.w * f;
    }
    ushort4 o;
    o.x = f2bf(fmaxf(acc.x, 0.f));
    o.y = f2bf(fmaxf(acc.y, 0.f));
    o.z = f2bf(fmaxf(acc.z, 0.f));
    o.w = f2bf(fmaxf(acc.w, 0.f));
    *(ushort4*)&h_out[(size_t)node * 256 + lane * 4] = o;
}

// ---------------------------------------------------------------------------
// Pooling + MLP head
// ---------------------------------------------------------------------------
__global__ __launch_bounds__(256) void pool_kernel(
    const unsigned short* __restrict__ h, const int* __restrict__ batch,
    float* __restrict__ g_feat)
{
    int g = blockIdx.x;
    int t = threadIdx.x;
    __shared__ int s_lo, s_hi;
    if (t == 0) {
        int lo = 0, hi = N_NODES;
        while (lo < hi) { int m = (lo + hi) >> 1; if (batch[m] < g) lo = m + 1; else hi = m; }
        s_lo = lo;
        int lo2 = lo, hi2 = N_NODES;
        while (lo2 < hi2) { int m = (lo2 + hi2) >> 1; if (batch[m] < g + 1) lo2 = m + 1; else hi2 = m; }
        s_hi = lo2;
    }
    __syncthreads();
    int lo = s_lo, hi = s_hi;
    float sum = 0.f, mx = 0.f;   // post-ReLU
    for (int n = lo; n < hi; ++n) {
        float v = bf2f(h[(size_t)n * 256 + t]);
        sum += v;
        mx = fmaxf(mx, v);
    }
    float cnt = (float)(hi - lo);
    g_feat[g * 512 + t]       = sum / fmaxf(cnt, 1.0f);
    g_feat[g * 512 + 256 + t] = (cnt > 0.f) ? mx : 0.f;
}

__global__ __launch_bounds__(128) void mlp_head(
    const float* __restrict__ g_feat,
    const float* __restrict__ fc1_w, const float* __restrict__ fc1_b,
    const float* __restrict__ fc2_w, const float* __restrict__ fc2_b,
    float* __restrict__ out)
{
    __shared__ float gf[512];
    __shared__ float partial[2];
    int g = blockIdx.x, t = threadIdx.x;
    for (int i = t; i < 512; i += 128) gf[i] = g_feat[g * 512 + i];
    __syncthreads();
    float acc = fc1_b[t];
    for (int i = 0; i < 512; ++i) acc += gf[i] * fc1_w[i * 128 + t];
    float h1 = fmaxf(acc, 0.f);
    float v = h1 * fc2_w[t];
    #pragma unroll
    for (int off = 32; off > 0; off >>= 1) v += __shfl_down(v, off);
    if ((t & 63) == 0) partial[t >> 6] = v;
    __syncthreads();
    if (t == 0) {
        float s = partial[0] + partial[1] + fc2_b[0];
        out[g] = 1.0f / (1.0f + expf(-s));
    }
}

// ---------------------------------------------------------------------------
// Launch
// ---------------------------------------------------------------------------
extern "C" void kernel_launch(void* const* d_in, const int* in_sizes, int n_in,
                              void* d_out, int out_size, void* d_ws, size_t ws_size,
                              hipStream_t stream) {
    const float* x          = (const float*)d_in[0];
    const int*   edge_index = (const int*)d_in[1];
    const int*   edge_attr  = (const int*)d_in[2];
    const int*   batch      = (const int*)d_in[3];
    const float* w0         = (const float*)d_in[4];
    const float* root0      = (const float*)d_in[5];
    const float* b0         = (const float*)d_in[6];
    const float* w_rest     = (const float*)d_in[7];
    const float* root_rest  = (const float*)d_in[8];
    const float* b_rest     = (const float*)d_in[9];
    const float* fc1_w      = (const float*)d_in[10];
    const float* fc1_b      = (const float*)d_in[11];
    const float* fc2_w      = (const float*)d_in[12];
    const float* fc2_b      = (const float*)d_in[13];
    float* out = (float*)d_out;

    const int* e_src = edge_index;
    const int* e_dst = edge_index + N_EDGES;

    char* p = (char*)d_ws;
    auto alloc = [&](size_t bytes) { char* q = p; p += (bytes + 255) & ~(size_t)255; return q; };
    unsigned short* x_bf   = (unsigned short*)alloc((size_t)M_PAD * D_IN * 2);   // 92 MB
    unsigned short* msgbuf = (unsigned short*)alloc((size_t)M_PAD * 1024 * 2);   // 123 MB
    unsigned short* hA     = (unsigned short*)alloc((size_t)M_PAD * 256 * 2);    // 31 MB
    unsigned short* hB     = (unsigned short*)alloc((size_t)M_PAD * 256 * 2);    // 31 MB
    unsigned short* Wt0    = (unsigned short*)alloc((size_t)N_TOT * D_IN * 2);
    unsigned short* WtR    = (unsigned short*)alloc((size_t)5 * 256 * N_TOT * 2);
    float*          ebias  = (float*)alloc(N_TOT * 4);
    float*          inv4   = (float*)alloc((size_t)N_NODES * 4 * 4);
    float*          g_feat = (float*)alloc((size_t)N_GRAPHS * 512 * 4);
    int*            deg4   = (int*)alloc((size_t)N_NODES * 4 * 4);
    int*            rp4    = (int*)alloc(((size_t)N_NODES * 4 + 1) * 4);
    int*            cursor4= (int*)alloc((size_t)N_NODES * 4 * 4);
    int*            bsum   = (int*)alloc(1024 * 4);
    int*            boff   = (int*)alloc(1024 * 4);
    int*            e_srcs = (int*)alloc((size_t)N_EDGES * 4);

    const int n4 = N_NODES * 4;                 // 240000
    const int nscan4 = cdiv(n4, 256);           // 938

    // --- prep ---
    hipMemsetAsync(deg4, 0, (size_t)n4 * 4, stream);
    convert_x<<<cdiv(M_PAD * D_IN / 4, 256), 256, 0, stream>>>(x, x_bf);
    pack_w0_t<<<960, 256, 0, stream>>>(root0, w0, Wt0);
    pack_wr_t<<<1600, 256, 0, stream>>>(root_rest, w_rest, WtR);
    build_bias<<<cdiv(N_TOT, 256), 256, 0, stream>>>(b0, ebias);
    deg4_count<<<cdiv(N_EDGES, 256), 256, 0, stream>>>(e_dst, edge_attr, deg4, N_EDGES);
    invert4<<<cdiv(n4, 256), 256, 0, stream>>>(deg4, inv4, n4);
    block_sum<<<nscan4, 256, 0, stream>>>(deg4, bsum, n4);
    scan_bsum<<<1, 1024, 0, stream>>>(bsum, boff, nscan4);
    block_scan_write<<<nscan4, 256, 0, stream>>>(deg4, boff, rp4, cursor4, n4, N_EDGES);
    place_edges4<<<cdiv(N_EDGES, 256), 256, 0, stream>>>(e_dst, e_src, edge_attr,
                                                         cursor4, e_srcs, N_EDGES);

    // --- layer 0: transform-first GEMM, XCD-swizzled flat grid ---
    gemm_l0<<<2345, 512, 0, stream>>>(x_bf, Wt0, ebias, hB, msgbuf, D_IN);
    aggregate0<<<cdiv(N_NODES, 4), 256, 0, stream>>>(hB, msgbuf, rp4, e_srcs, inv4, hA);

    // --- layers 1..5: fused gather+mean+GEMM (round-4 structure) ---
    unsigned short* cur = hA;
    unsigned short* nxt = hB;
    for (int L = 1; L < N_LAYERS; ++L) {
        rgcn_layer<<<M_PAD / BM_L, 512, 0, stream>>>(
            cur, WtR + (size_t)(L - 1) * 256 * N_TOT, b_rest + (size_t)(L - 1) * 256,
            rp4, e_srcs, inv4, nxt);
        unsigned short* t = cur; cur = nxt; nxt = t;
    }
    // final h in cur

    pool_kernel<<<N_GRAPHS, 256, 0, stream>>>(cur, batch, g_feat);
    mlp_head<<<N_GRAPHS, 128, 0, stream>>>(g_feat, fc1_w, fc1_b, fc2_w, fc2_b, out);
}

// Round 9
// 1351.456 us; speedup vs baseline: 1.2894x; 1.0861x over previous
//
#include <hip/hip_runtime.h>
#include <hip/hip_bf16.h>

#define N_NODES  60000
#define N_EDGES  240000
#define N_REL    4
#define N_GRAPHS 128
#define D_IN     768
#define D_H      256
#define N_LAYERS 6
#define M_PAD    60032            // 469 * 128
#define N_TOT    1280             // L0 cols: 256 root + 4*256 msg; also W k-stride

static inline int cdiv(int a, int b) { return (a + b - 1) / b; }

typedef __attribute__((ext_vector_type(8))) short short8;
typedef __attribute__((ext_vector_type(4))) float f32x4;

__device__ __forceinline__ float bf2f(unsigned short u) {
    union { unsigned int i; float f; } c; c.i = ((unsigned int)u) << 16; return c.f;
}
__device__ __forceinline__ float bflo(unsigned int u) {
    union { unsigned int i; float f; } c; c.i = u << 16; return c.f;
}
__device__ __forceinline__ float bfhi(unsigned int u) {
    union { unsigned int i; float f; } c; c.i = u & 0xffff0000u; return c.f;
}
__device__ __forceinline__ unsigned short f2bf(float f) {
    union { float f; unsigned int i; } c; c.f = f;
    unsigned int i = c.i;
    unsigned int r = (i + 0x7FFFu + ((i >> 16) & 1u)) >> 16;   // RNE
    return (unsigned short)r;
}

__device__ __forceinline__ void gload16(const void* g, void* l) {
    __builtin_amdgcn_global_load_lds((const __attribute__((address_space(1))) void*)g,
                                     (__attribute__((address_space(3))) void*)l, 16, 0, 0);
}

// am[8] covers 32 bf16 columns
__device__ __forceinline__ void accum32(float4* am, uint4 v0, uint4 v1, uint4 v2, uint4 v3) {
    am[0].x += bflo(v0.x); am[0].y += bfhi(v0.x);
    am[0].z += bflo(v0.y); am[0].w += bfhi(v0.y);
    am[1].x += bflo(v0.z); am[1].y += bfhi(v0.z);
    am[1].z += bflo(v0.w); am[1].w += bfhi(v0.w);
    am[2].x += bflo(v1.x); am[2].y += bfhi(v1.x);
    am[2].z += bflo(v1.y); am[2].w += bfhi(v1.y);
    am[3].x += bflo(v1.z); am[3].y += bfhi(v1.z);
    am[3].z += bflo(v1.w); am[3].w += bfhi(v1.w);
    am[4].x += bflo(v2.x); am[4].y += bfhi(v2.x);
    am[4].z += bflo(v2.y); am[4].w += bfhi(v2.y);
    am[5].x += bflo(v2.z); am[5].y += bfhi(v2.z);
    am[5].z += bflo(v2.w); am[5].w += bfhi(v2.w);
    am[6].x += bflo(v3.x); am[6].y += bfhi(v3.x);
    am[6].z += bflo(v3.y); am[6].w += bfhi(v3.y);
    am[7].x += bflo(v3.z); am[7].y += bfhi(v3.z);
    am[7].z += bflo(v3.w); am[7].w += bfhi(v3.w);
}

__device__ __forceinline__ void accum32s(float4* am, uint4 v0, uint4 v1, uint4 v2, uint4 v3, float sc) {
    am[0].x += bflo(v0.x) * sc; am[0].y += bfhi(v0.x) * sc;
    am[0].z += bflo(v0.y) * sc; am[0].w += bfhi(v0.y) * sc;
    am[1].x += bflo(v0.z) * sc; am[1].y += bfhi(v0.z) * sc;
    am[1].z += bflo(v0.w) * sc; am[1].w += bfhi(v0.w) * sc;
    am[2].x += bflo(v1.x) * sc; am[2].y += bfhi(v1.x) * sc;
    am[2].z += bflo(v1.y) * sc; am[2].w += bfhi(v1.y) * sc;
    am[3].x += bflo(v1.z) * sc; am[3].y += bfhi(v1.z) * sc;
    am[3].z += bflo(v1.w) * sc; am[3].w += bfhi(v1.w) * sc;
    am[4].x += bflo(v2.x) * sc; am[4].y += bfhi(v2.x) * sc;
    am[4].z += bflo(v2.y) * sc; am[4].w += bfhi(v2.y) * sc;
    am[5].x += bflo(v2.z) * sc; am[5].y += bfhi(v2.z) * sc;
    am[5].z += bflo(v2.w) * sc; am[5].w += bfhi(v2.w) * sc;
    am[6].x += bflo(v3.x) * sc; am[6].y += bfhi(v3.x) * sc;
    am[6].z += bflo(v3.y) * sc; am[6].w += bfhi(v3.y) * sc;
    am[7].x += bflo(v3.z) * sc; am[7].y += bfhi(v3.z) * sc;
    am[7].z += bflo(v3.w) * sc; am[7].w += bfhi(v3.w) * sc;
}

// ---------------------------------------------------------------------------
// Layer-0 GEMM (transform-first): A[M_PAD,768] bf16 @ Wt0[1280,768]^T.
// XCD-swizzled flat grid (measured: FETCH 264 -> 87 MB).
// ---------------------------------------------------------------------------
__global__ __launch_bounds__(512) void gemm_l0(
    const unsigned short* __restrict__ A,
    const unsigned short* __restrict__ Bt,
    const float* __restrict__ bias,
    unsigned short* __restrict__ out_root,
    unsigned short* __restrict__ out_msg,
    int K)
{
    __shared__ unsigned short As[128 * 32];
    __shared__ unsigned short Bs[256 * 32];

    const int tid  = threadIdx.x;
    const int wave = tid >> 6, lane = tid & 63;

    int b = blockIdx.x;
    int bm, bn;
    if (b < 2320) { int grp = b / 40, rem = b % 40; bm = (grp * 8 + (rem & 7)) * 128; bn = (rem >> 3) * 256; }
    else          { int rem = b - 2320; bm = (464 + rem % 5) * 128; bn = (rem / 5) * 256; }

    const int wm = (wave & 1) * 64, wn = (wave >> 1) * 64;

    const int lr = lane >> 2;
    const int kg = ((lane & 3) ^ ((lr ^ (lr >> 2)) & 3)) * 8;   // swizzled k-chunk
    const unsigned short* gsrc[3];
    unsigned short* ldst[3];
    #pragma unroll
    for (int j = 0; j < 3; ++j) {
        int g = wave * 3 + j;
        if (g < 8) {
            gsrc[j] = A + (size_t)(bm + g * 16 + lr) * K + kg;
            ldst[j] = As + g * 16 * 32;
        } else {
            gsrc[j] = Bt + (size_t)(bn + (g - 8) * 16 + lr) * K + kg;
            ldst[j] = Bs + (g - 8) * 16 * 32;
        }
    }

    f32x4 acc[4][4] = {};
    const int fr = lane & 15;
    const int qsw = (((lane >> 4) ^ fr ^ (fr >> 2)) & 3) * 8;

    for (int k0 = 0; k0 < K; k0 += 32) {
        gload16(gsrc[0] + k0, ldst[0]);
        gload16(gsrc[1] + k0, ldst[1]);
        gload16(gsrc[2] + k0, ldst[2]);
        __syncthreads();

        short8 a[4], bb[4];
        #pragma unroll
        for (int t = 0; t < 4; ++t) {
            a[t]  = *(const short8*)&As[(wm + t * 16 + fr) * 32 + qsw];
            bb[t] = *(const short8*)&Bs[(wn + t * 16 + fr) * 32 + qsw];
        }
        #pragma unroll
        for (int mt = 0; mt < 4; ++mt)
            #pragma unroll
            for (int nt = 0; nt < 4; ++nt)
                acc[mt][nt] = __builtin_amdgcn_mfma_f32_16x16x32_bf16(
                    a[mt], bb[nt], acc[mt][nt], 0, 0, 0);
        __syncthreads();
    }

    const bool is_root = (bn == 0);   // block-uniform
    #pragma unroll
    for (int mt = 0; mt < 4; ++mt) {
        #pragma unroll
        for (int nt = 0; nt < 4; ++nt) {
            int col = bn + wn + nt * 16 + fr;
            float bv = bias[col];
            #pragma unroll
            for (int r = 0; r < 4; ++r) {
                int row = bm + wm + mt * 16 + ((lane >> 4) << 2) + r;
                float v = acc[mt][nt][r] + bv;
                if (is_root) out_root[(size_t)row * 256 + col] = f2bf(v);
                else         out_msg[(size_t)row * 1024 + (col - 256)] = f2bf(v);
            }
        }
    }
}

// ---------------------------------------------------------------------------
// Mid-layer GEMM: A' = [means | h] (K = 1280), Bt[256][1280], 128x128 tile,
// 256 threads (m97 structure: 16 KB LDS, high blocks/CU).
// Epilogue: +bias, ReLU, bf16 -> h_out.
// ---------------------------------------------------------------------------
__global__ __launch_bounds__(256) void gemm_mid(
    const unsigned short* __restrict__ means,   // [M_PAD, 1024]
    const unsigned short* __restrict__ hprev,   // [M_PAD, 256]
    const unsigned short* __restrict__ Bt,      // [256][1280]
    const float* __restrict__ bias,             // [256]
    unsigned short* __restrict__ h_out)         // [M_PAD, 256]
{
    __shared__ unsigned short As[128 * 32];
    __shared__ unsigned short Bs[128 * 32];

    const int tid  = threadIdx.x;
    const int wave = tid >> 6, lane = tid & 63;
    const int b  = blockIdx.x;
    const int bm = (b >> 1) * 128;
    const int bn = (b & 1) * 128;
    const int wm = (wave & 1) * 64, wn = (wave >> 1) * 64;

    const int lr = lane >> 2;
    const int kg = ((lane & 3) ^ ((lr ^ (lr >> 2)) & 3)) * 8;

    // waves 0,1 stage A (8 insts of 16 rows); waves 2,3 stage B
    const unsigned short* srcM[4];
    const unsigned short* srcH[4];
    const unsigned short* srcB[4];
    unsigned short* ldst[4];
    #pragma unroll
    for (int j = 0; j < 4; ++j) {
        int g = wave * 4 + j;
        if (g < 8) {
            int row = bm + g * 16 + lr;
            srcM[j] = means + (size_t)row * 1024 + kg;
            srcH[j] = hprev + (size_t)row * 256 + kg;
            srcB[j] = nullptr;
            ldst[j] = As + g * 512;
        } else {
            int row = bn + (g - 8) * 16 + lr;
            srcB[j] = Bt + (size_t)row * N_TOT + kg;
            srcM[j] = srcH[j] = nullptr;
            ldst[j] = Bs + (g - 8) * 512;
        }
    }

    f32x4 acc[4][4] = {};
    const int fr = lane & 15;
    const int qsw = (((lane >> 4) ^ fr ^ (fr >> 2)) & 3) * 8;

    // ---- section 1: k in [0,1024) from means ----
    for (int k0 = 0; k0 < 1024; k0 += 32) {
        if (wave < 2) {
            #pragma unroll
            for (int j = 0; j < 4; ++j) gload16(srcM[j] + k0, ldst[j]);
        } else {
            #pragma unroll
            for (int j = 0; j < 4; ++j) gload16(srcB[j] + k0, ldst[j]);
        }
        __syncthreads();
        short8 a[4], bb[4];
        #pragma unroll
        for (int t = 0; t < 4; ++t) {
            a[t]  = *(const short8*)&As[(wm + t * 16 + fr) * 32 + qsw];
            bb[t] = *(const short8*)&Bs[(wn + t * 16 + fr) * 32 + qsw];
        }
        #pragma unroll
        for (int mt = 0; mt < 4; ++mt)
            #pragma unroll
            for (int nt = 0; nt < 4; ++nt)
                acc[mt][nt] = __builtin_amdgcn_mfma_f32_16x16x32_bf16(
                    a[mt], bb[nt], acc[mt][nt], 0, 0, 0);
        __syncthreads();
    }
    // ---- section 2: k in [1024,1280) from hprev ----
    for (int k0 = 0; k0 < 256; k0 += 32) {
        if (wave < 2) {
            #pragma unroll
            for (int j = 0; j < 4; ++j) gload16(srcH[j] + k0, ldst[j]);
        } else {
            #pragma unroll
            for (int j = 0; j < 4; ++j) gload16(srcB[j] + 1024 + k0, ldst[j]);
        }
        __syncthreads();
        short8 a[4], bb[4];
        #pragma unroll
        for (int t = 0; t < 4; ++t) {
            a[t]  = *(const short8*)&As[(wm + t * 16 + fr) * 32 + qsw];
            bb[t] = *(const short8*)&Bs[(wn + t * 16 + fr) * 32 + qsw];
        }
        #pragma unroll
        for (int mt = 0; mt < 4; ++mt)
            #pragma unroll
            for (int nt = 0; nt < 4; ++nt)
                acc[mt][nt] = __builtin_amdgcn_mfma_f32_16x16x32_bf16(
                    a[mt], bb[nt], acc[mt][nt], 0, 0, 0);
        __syncthreads();
    }

    // epilogue
    #pragma unroll
    for (int mt = 0; mt < 4; ++mt) {
        #pragma unroll
        for (int nt = 0; nt < 4; ++nt) {
            int col = bn + wn + nt * 16 + fr;
            float bv = bias[col];
            #pragma unroll
            for (int rg = 0; rg < 4; ++rg) {
                int row = bm + wm + mt * 16 + ((lane >> 4) << 2) + rg;
                float v = fmaxf(acc[mt][nt][rg] + bv, 0.f);
                h_out[(size_t)row * 256 + col] = f2bf(v);
            }
        }
    }
}

// ---------------------------------------------------------------------------
// Per-relation means: lane-per-node gather (64 independent addrs per inst),
// no LDS, no barriers. Writes means[node*1024 + r*256 + slice].
// ---------------------------------------------------------------------------
__global__ __launch_bounds__(512) void agg_means(
    const unsigned short* __restrict__ h,       // [M_PAD,256]
    const int* __restrict__ rp4, const int* __restrict__ e_sr,
    const float* __restrict__ inv4,
    unsigned short* __restrict__ means)         // [M_PAD,1024]
{
    const int wave = threadIdx.x >> 6, lane = threadIdx.x & 63;
    const int node = blockIdx.x * 64 + lane;
    const int cq = wave * 32;                    // 32-short slice of 256
    if (node >= N_NODES) return;
    float4 iv = *(const float4*)&inv4[(size_t)node * 4];

    #pragma unroll
    for (int r = 0; r < 4; ++r) {
        float4 am[8];
        #pragma unroll
        for (int j = 0; j < 8; ++j) am[j] = make_float4(0.f, 0.f, 0.f, 0.f);

        int lo = rp4[node * 4 + r], hi = rp4[node * 4 + r + 1];
        int e = lo;
        for (; e + 1 < hi; e += 2) {
            int s0 = e_sr[e] & 0xffff, s1 = e_sr[e + 1] & 0xffff;
            const uint4* p0 = (const uint4*)(h + (size_t)s0 * 256 + cq);
            const uint4* p1 = (const uint4*)(h + (size_t)s1 * 256 + cq);
            uint4 a0 = p0[0], a1 = p0[1], a2 = p0[2], a3 = p0[3];
            uint4 b0 = p1[0], b1 = p1[1], b2 = p1[2], b3 = p1[3];
            accum32(am, a0, a1, a2, a3);
            accum32(am, b0, b1, b2, b3);
        }
        if (e < hi) {
            int s0 = e_sr[e] & 0xffff;
            const uint4* p0 = (const uint4*)(h + (size_t)s0 * 256 + cq);
            accum32(am, p0[0], p0[1], p0[2], p0[3]);
        }
        float sc = (r == 0) ? iv.x : (r == 1) ? iv.y : (r == 2) ? iv.z : iv.w;
        unsigned short* op = means + (size_t)node * 1024 + (r << 8) + cq;
        #pragma unroll
        for (int j = 0; j < 8; ++j) {
            ushort4 o;
            o.x = f2bf(am[j].x * sc); o.y = f2bf(am[j].y * sc);
            o.z = f2bf(am[j].z * sc); o.w = f2bf(am[j].w * sc);
            *(ushort4*)(op + j * 4) = o;
        }
    }
}

// ---------------------------------------------------------------------------
// Layer-0 aggregate: lane-per-node, merged edge loop over packed (src|rel<<16).
// h0 = relu(root + sum_e inv[rel_e] * msg[src_e, rel_e])
// ---------------------------------------------------------------------------
__global__ __launch_bounds__(512) void aggregate0(
    const unsigned short* __restrict__ rootb,   // [M_PAD,256]
    const unsigned short* __restrict__ msg,     // [M_PAD,1024]
    const int* __restrict__ rp4, const int* __restrict__ e_sr,
    const float* __restrict__ inv4,
    unsigned short* __restrict__ h_out)         // [M_PAD,256]
{
    const int wave = threadIdx.x >> 6, lane = threadIdx.x & 63;
    const int node = blockIdx.x * 64 + lane;
    const int cq = wave * 32;
    if (node >= N_NODES) return;
    float4 iv = *(const float4*)&inv4[(size_t)node * 4];

    float4 am[8];
    #pragma unroll
    for (int j = 0; j < 8; ++j) am[j] = make_float4(0.f, 0.f, 0.f, 0.f);
    {
        const uint4* rp = (const uint4*)(rootb + (size_t)node * 256 + cq);
        accum32(am, rp[0], rp[1], rp[2], rp[3]);
    }

    int lo = rp4[node * 4], hi = rp4[node * 4 + 4];
    int e = lo;
    for (; e + 1 < hi; e += 2) {
        int sr0 = e_sr[e], sr1 = e_sr[e + 1];
        int s0 = sr0 & 0xffff, r0 = sr0 >> 16;
        int s1 = sr1 & 0xffff, r1 = sr1 >> 16;
        float c0 = (r0 == 0) ? iv.x : (r0 == 1) ? iv.y : (r0 == 2) ? iv.z : iv.w;
        float c1 = (r1 == 0) ? iv.x : (r1 == 1) ? iv.y : (r1 == 2) ? iv.z : iv.w;
        const uint4* p0 = (const uint4*)(msg + (size_t)s0 * 1024 + (r0 << 8) + cq);
        const uint4* p1 = (const uint4*)(msg + (size_t)s1 * 1024 + (r1 << 8) + cq);
        uint4 a0 = p0[0], a1 = p0[1], a2 = p0[2], a3 = p0[3];
        uint4 b0 = p1[0], b1 = p1[1], b2 = p1[2], b3 = p1[3];
        accum32s(am, a0, a1, a2, a3, c0);
        accum32s(am, b0, b1, b2, b3, c1);
    }
    if (e < hi) {
        int sr0 = e_sr[e];
        int s0 = sr0 & 0xffff, r0 = sr0 >> 16;
        float c0 = (r0 == 0) ? iv.x : (r0 == 1) ? iv.y : (r0 == 2) ? iv.z : iv.w;
        const uint4* p0 = (const uint4*)(msg + (size_t)s0 * 1024 + (r0 << 8) + cq);
        accum32s(am, p0[0], p0[1], p0[2], p0[3], c0);
    }
    unsigned short* op = h_out + (size_t)node * 256 + cq;
    #pragma unroll
    for (int j = 0; j < 8; ++j) {
        ushort4 o;
        o.x = f2bf(fmaxf(am[j].x, 0.f)); o.y = f2bf(fmaxf(am[j].y, 0.f));
        o.z = f2bf(fmaxf(am[j].z, 0.f)); o.w = f2bf(fmaxf(am[j].w, 0.f));
        *(ushort4*)(op + j * 4) = o;
    }
}

// ---------------------------------------------------------------------------
// Prep kernels
// ---------------------------------------------------------------------------
__global__ void convert_x(const float* __restrict__ x, unsigned short* __restrict__ xb) {
    size_t i = ((size_t)blockIdx.x * 256 + threadIdx.x) * 4;
    if (i >= (size_t)M_PAD * D_IN) return;
    ushort4 o;
    if (i < (size_t)N_NODES * D_IN) {
        float4 v = *(const float4*)&x[i];
        o.x = f2bf(v.x); o.y = f2bf(v.y); o.z = f2bf(v.z); o.w = f2bf(v.w);
    } else {
        o.x = o.y = o.z = o.w = 0;
    }
    *(ushort4*)&xb[i] = o;
}

__global__ __launch_bounds__(256) void pack_w0_t(
    const float* __restrict__ root0, const float* __restrict__ w0,
    unsigned short* __restrict__ Wt0)
{
    __shared__ float t[32][33];
    int b = blockIdx.x;                 // 5 * 24 * 8 = 960
    int i  = b / 192;
    int rem = b % 192;
    int kb = (rem / 8) * 32;
    int nb = (rem % 8) * 32;
    const float* S = (i == 0) ? root0 : w0 + (size_t)(i - 1) * D_IN * 256;
    int tx = threadIdx.x & 31, ty = threadIdx.x >> 5;   // 32 x 8
    #pragma unroll
    for (int j = 0; j < 4; ++j)
        t[ty + j * 8][tx] = S[(size_t)(kb + ty + j * 8) * 256 + nb + tx];
    __syncthreads();
    #pragma unroll
    for (int j = 0; j < 4; ++j)
        Wt0[(size_t)(i * 256 + nb + ty + j * 8) * D_IN + kb + tx] = f2bf(t[tx][ty + j * 8]);
}

__global__ __launch_bounds__(256) void pack_wr_t(
    const float* __restrict__ root_rest, const float* __restrict__ w_rest,
    unsigned short* __restrict__ WtR)
{
    __shared__ float t[32][33];
    int b = blockIdx.x;                 // 25 * 8 * 8 = 1600
    int m = b / 64;                     // matrix id: l*5 + j
    int rem = b % 64;
    int kb = (rem / 8) * 32;
    int nb = (rem % 8) * 32;
    int l = m / 5, j = m % 5;
    const float* S = (j < 4) ? w_rest + (size_t)(l * 4 + j) * 256 * 256
                             : root_rest + (size_t)l * 256 * 256;
    int tx = threadIdx.x & 31, ty = threadIdx.x >> 5;
    #pragma unroll
    for (int jj = 0; jj < 4; ++jj)
        t[ty + jj * 8][tx] = S[(size_t)(kb + ty + jj * 8) * 256 + nb + tx];
    __syncthreads();
    #pragma unroll
    for (int jj = 0; jj < 4; ++jj)
        WtR[(size_t)(l * 256 + nb + ty + jj * 8) * N_TOT + j * 256 + kb + tx] =
            f2bf(t[tx][ty + jj * 8]);
}

__global__ void build_bias(const float* __restrict__ b0, float* __restrict__ eb) {
    int i = blockIdx.x * 256 + threadIdx.x;
    if (i < N_TOT) eb[i] = (i < 256) ? b0[i] : 0.f;
}

// ---------------------------------------------------------------------------
// (dst, rel)-sorted CSR over 4*N segments
// ---------------------------------------------------------------------------
__global__ void deg4_count(const int* __restrict__ dst, const int* __restrict__ rel,
                           int* __restrict__ deg4, int E) {
    int e = blockIdx.x * 256 + threadIdx.x;
    if (e < E) atomicAdd(&deg4[dst[e] * 4 + rel[e]], 1);
}

__global__ void invert4(const int* __restrict__ deg4, float* __restrict__ inv4, int n) {
    int i = blockIdx.x * 256 + threadIdx.x;
    if (i < n) inv4[i] = 1.0f / (float)max(deg4[i], 1);
}

__global__ __launch_bounds__(256) void block_sum(const int* __restrict__ deg,
                                                 int* __restrict__ bsum, int n) {
    __shared__ int s[256];
    int i = blockIdx.x * 256 + threadIdx.x;
    s[threadIdx.x] = (i < n) ? deg[i] : 0;
    __syncthreads();
    for (int o = 128; o > 0; o >>= 1) {
        if (threadIdx.x < o) s[threadIdx.x] += s[threadIdx.x + o];
        __syncthreads();
    }
    if (threadIdx.x == 0) bsum[blockIdx.x] = s[0];
}

__global__ __launch_bounds__(1024) void scan_bsum(const int* __restrict__ bsum,
                                                  int* __restrict__ boff, int nb) {
    __shared__ int s[1024];
    int t = threadIdx.x;
    int v0 = (t < nb) ? bsum[t] : 0;
    s[t] = v0;
    __syncthreads();
    for (int o = 1; o < 1024; o <<= 1) {
        int v = (t >= o) ? s[t - o] : 0;
        __syncthreads();
        s[t] += v;
        __syncthreads();
    }
    if (t < nb) boff[t] = s[t] - v0;   // exclusive
}

__global__ __launch_bounds__(256) void block_scan_write(
    const int* __restrict__ deg, const int* __restrict__ boff,
    int* __restrict__ row_ptr, int* __restrict__ cursor, int n, int total) {
    __shared__ int s[256];
    int t = threadIdx.x;
    int i = blockIdx.x * 256 + t;
    int v = (i < n) ? deg[i] : 0;
    s[t] = v;
    __syncthreads();
    for (int o = 1; o < 256; o <<= 1) {
        int u = (t >= o) ? s[t - o] : 0;
        __syncthreads();
        s[t] += u;
        __syncthreads();
    }
    int excl = s[t] - v + boff[blockIdx.x];
    if (i < n) { row_ptr[i] = excl; cursor[i] = excl; }
    if (blockIdx.x == 0 && t == 0) row_ptr[n] = total;
}

__global__ void place_edges4(const int* __restrict__ dst, const int* __restrict__ src,
                             const int* __restrict__ rel, int* __restrict__ cursor,
                             int* __restrict__ e_sr, int E) {
    int e = blockIdx.x * 256 + threadIdx.x;
    if (e < E) {
        int d = dst[e], r = rel[e], s = src[e];
        int pI = atomicAdd(&cursor[d * 4 + r], 1);
        e_sr[pI] = s | (r << 16);   // src < 65536
    }
}

// ---------------------------------------------------------------------------
// Pooling + MLP head
// ---------------------------------------------------------------------------
__global__ __launch_bounds__(256) void pool_kernel(
    const unsigned short* __restrict__ h, const int* __restrict__ batch,
    float* __restrict__ g_feat)
{
    int g = blockIdx.x;
    int t = threadIdx.x;
    __shared__ int s_lo, s_hi;
    if (t == 0) {
        int lo = 0, hi = N_NODES;
        while (lo < hi) { int m = (lo + hi) >> 1; if (batch[m] < g) lo = m + 1; else hi = m; }
        s_lo = lo;
        int lo2 = lo, hi2 = N_NODES;
        while (lo2 < hi2) { int m = (lo2 + hi2) >> 1; if (batch[m] < g + 1) lo2 = m + 1; else hi2 = m; }
        s_hi = lo2;
    }
    __syncthreads();
    int lo = s_lo, hi = s_hi;
    float sum = 0.f, mx = 0.f;   // post-ReLU
    for (int n = lo; n < hi; ++n) {
        float v = bf2f(h[(size_t)n * 256 + t]);
        sum += v;
        mx = fmaxf(mx, v);
    }
    float cnt = (float)(hi - lo);
    g_feat[g * 512 + t]       = sum / fmaxf(cnt, 1.0f);
    g_feat[g * 512 + 256 + t] = (cnt > 0.f) ? mx : 0.f;
}

__global__ __launch_bounds__(128) void mlp_head(
    const float* __restrict__ g_feat,
    const float* __restrict__ fc1_w, const float* __restrict__ fc1_b,
    const float* __restrict__ fc2_w, const float* __restrict__ fc2_b,
    float* __restrict__ out)
{
    __shared__ float gf[512];
    __shared__ float partial[2];
    int g = blockIdx.x, t = threadIdx.x;
    for (int i = t; i < 512; i += 128) gf[i] = g_feat[g * 512 + i];
    __syncthreads();
    float acc = fc1_b[t];
    for (int i = 0; i < 512; ++i) acc += gf[i] * fc1_w[i * 128 + t];
    float h1 = fmaxf(acc, 0.f);
    float v = h1 * fc2_w[t];
    #pragma unroll
    for (int off = 32; off > 0; off >>= 1) v += __shfl_down(v, off);
    if ((t & 63) == 0) partial[t >> 6] = v;
    __syncthreads();
    if (t == 0) {
        float s = partial[0] + partial[1] + fc2_b[0];
        out[g] = 1.0f / (1.0f + expf(-s));
    }
}

// ---------------------------------------------------------------------------
// Launch
// ---------------------------------------------------------------------------
extern "C" void kernel_launch(void* const* d_in, const int* in_sizes, int n_in,
                              void* d_out, int out_size, void* d_ws, size_t ws_size,
                              hipStream_t stream) {
    const float* x          = (const float*)d_in[0];
    const int*   edge_index = (const int*)d_in[1];
    const int*   edge_attr  = (const int*)d_in[2];
    const int*   batch      = (const int*)d_in[3];
    const float* w0         = (const float*)d_in[4];
    const float* root0      = (const float*)d_in[5];
    const float* b0         = (const float*)d_in[6];
    const float* w_rest     = (const float*)d_in[7];
    const float* root_rest  = (const float*)d_in[8];
    const float* b_rest     = (const float*)d_in[9];
    const float* fc1_w      = (const float*)d_in[10];
    const float* fc1_b      = (const float*)d_in[11];
    const float* fc2_w      = (const float*)d_in[12];
    const float* fc2_b      = (const float*)d_in[13];
    float* out = (float*)d_out;

    const int* e_src = edge_index;
    const int* e_dst = edge_index + N_EDGES;

    char* p = (char*)d_ws;
    auto alloc = [&](size_t bytes) { char* q = p; p += (bytes + 255) & ~(size_t)255; return q; };
    unsigned short* x_bf   = (unsigned short*)alloc((size_t)M_PAD * D_IN * 2);   // 92 MB
    unsigned short* msgbuf = (unsigned short*)alloc((size_t)M_PAD * 1024 * 2);   // 123 MB (msg / means)
    unsigned short* hA     = (unsigned short*)alloc((size_t)M_PAD * 256 * 2);    // 31 MB
    unsigned short* hB     = (unsigned short*)alloc((size_t)M_PAD * 256 * 2);    // 31 MB
    unsigned short* Wt0    = (unsigned short*)alloc((size_t)N_TOT * D_IN * 2);
    unsigned short* WtR    = (unsigned short*)alloc((size_t)5 * 256 * N_TOT * 2);
    float*          ebias  = (float*)alloc(N_TOT * 4);
    float*          inv4   = (float*)alloc((size_t)N_NODES * 4 * 4);
    float*          g_feat = (float*)alloc((size_t)N_GRAPHS * 512 * 4);
    int*            deg4   = (int*)alloc((size_t)N_NODES * 4 * 4);
    int*            rp4    = (int*)alloc(((size_t)N_NODES * 4 + 1) * 4);
    int*            cursor4= (int*)alloc((size_t)N_NODES * 4 * 4);
    int*            bsum   = (int*)alloc(1024 * 4);
    int*            boff   = (int*)alloc(1024 * 4);
    int*            e_sr   = (int*)alloc((size_t)N_EDGES * 4);

    const int n4 = N_NODES * 4;                 // 240000
    const int nscan4 = cdiv(n4, 256);           // 938
    const int ngrid = cdiv(N_NODES, 64);        // 938

    // --- prep ---
    hipMemsetAsync(deg4, 0, (size_t)n4 * 4, stream);
    convert_x<<<cdiv(M_PAD * D_IN / 4, 256), 256, 0, stream>>>(x, x_bf);
    pack_w0_t<<<960, 256, 0, stream>>>(root0, w0, Wt0);
    pack_wr_t<<<1600, 256, 0, stream>>>(root_rest, w_rest, WtR);
    build_bias<<<cdiv(N_TOT, 256), 256, 0, stream>>>(b0, ebias);
    deg4_count<<<cdiv(N_EDGES, 256), 256, 0, stream>>>(e_dst, edge_attr, deg4, N_EDGES);
    invert4<<<cdiv(n4, 256), 256, 0, stream>>>(deg4, inv4, n4);
    block_sum<<<nscan4, 256, 0, stream>>>(deg4, bsum, n4);
    scan_bsum<<<1, 1024, 0, stream>>>(bsum, boff, nscan4);
    block_scan_write<<<nscan4, 256, 0, stream>>>(deg4, boff, rp4, cursor4, n4, N_EDGES);
    place_edges4<<<cdiv(N_EDGES, 256), 256, 0, stream>>>(e_dst, e_src, edge_attr,
                                                         cursor4, e_sr, N_EDGES);

    // --- layer 0: transform-first GEMM + lane-per-node aggregate ---
    gemm_l0<<<2345, 512, 0, stream>>>(x_bf, Wt0, ebias, hB, msgbuf, D_IN);
    aggregate0<<<ngrid, 512, 0, stream>>>(hB, msgbuf, rp4, e_sr, inv4, hA);

    // --- layers 1..5: decoupled means-gather + dense GEMM ---
    unsigned short* cur = hA;
    unsigned short* nxt = hB;
    for (int L = 1; L < N_LAYERS; ++L) {
        agg_means<<<ngrid, 512, 0, stream>>>(cur, rp4, e_sr, inv4, msgbuf);
        gemm_mid<<<2 * (M_PAD / 128), 256, 0, stream>>>(
            msgbuf, cur, WtR + (size_t)(L - 1) * 256 * N_TOT,
            b_rest + (size_t)(L - 1) * 256, nxt);
        unsigned short* t = cur; cur = nxt; nxt = t;
    }
    // final h in cur

    pool_kernel<<<N_GRAPHS, 256, 0, stream>>>(cur, batch, g_feat);
    mlp_head<<<N_GRAPHS, 128, 0, stream>>>(g_feat, fc1_w, fc1_b, fc2_w, fc2_b, out);
}